// Round 9
// baseline (382.632 us; speedup 1.0000x reference)
//
#include <hip/hip_runtime.h>
#include <math.h>

#define NODES 20000
#define MPAD  20096          // NODES padded to multiple of 128 (GEMM M-tiles)
#define EDGES 320000
#define EPSV  1e-5f
#define LOG2E 1.4426950408889634f

// k_prep block ranges
#define PREP_CNT   1250                    // count: 1250*256 >= EDGES
#define PREP_CAST  5000                    // cast: NODES*256/4/256
#define PREP_TR    512                     // 4 matrices * 128 tiles
#define PREP_TOTAL (PREP_CNT + PREP_CAST + PREP_TR + 1)

typedef short bf16x8 __attribute__((ext_vector_type(8)));
typedef float f32x4  __attribute__((ext_vector_type(4)));
typedef float f2     __attribute__((ext_vector_type(2)));

__device__ __forceinline__ unsigned short f2bf(float f) {
    unsigned int u = __float_as_uint(f);
    u = (u + 0x7fffu + ((u >> 16) & 1u)) >> 16;
    return (unsigned short)u;
}
__device__ __forceinline__ float bf2f(unsigned short h) {
    return __uint_as_float(((unsigned int)h) << 16);
}

// ---------------- fused prep: edge-count + x cast + 4x weight transpose + zeros
__global__ void k_prep(const int* __restrict__ dst, int* __restrict__ counts,
                       const float* __restrict__ x, unsigned short* __restrict__ xb,
                       const float* __restrict__ Wl1, const float* __restrict__ Wr1,
                       const float* __restrict__ Wl2, const float* __restrict__ Wr2,
                       unsigned short* __restrict__ o1l, unsigned short* __restrict__ o1r,
                       unsigned short* __restrict__ o2l, unsigned short* __restrict__ o2r,
                       float* __restrict__ acc, float* __restrict__ colsum) {
    int b = blockIdx.x;
    int t = threadIdx.x;
    if (b < PREP_CNT) {
        int e = b * 256 + t;
        if (e < EDGES) atomicAdd(&counts[dst[e]], 1);
    } else if (b < PREP_CNT + PREP_CAST) {
        int i = ((b - PREP_CNT) * 256 + t) * 4;
        float4 v = *(const float4*)(x + i);
        xb[i + 0] = f2bf(v.x); xb[i + 1] = f2bf(v.y);
        xb[i + 2] = f2bf(v.z); xb[i + 3] = f2bf(v.w);
    } else if (b < PREP_CNT + PREP_CAST + PREP_TR) {
        __shared__ float tile[32][33];
        int zz = b - PREP_CNT - PREP_CAST;     // 0..511
        int z = zz >> 7;                        // matrix 0..3
        int idx = zz & 127;                     // tile within matrix
        const float* W = (z == 0) ? Wl1 : (z == 1) ? Wr1 : (z == 2) ? Wl2 : Wr2;
        unsigned short* Wt = (z == 0) ? o1l : (z == 1) ? o1r : (z == 2) ? o2l : o2r;
        int K = (z < 2) ? 256 : 512, N = (z < 2) ? 512 : 256;
        int nb = N / 32;
        int n0 = (idx % nb) * 32, k0 = (idx / nb) * 32;
        int tx = t & 31, ty = t >> 5;          // (32,8) layout
#pragma unroll
        for (int j = 0; j < 4; j++)
            tile[ty + j * 8][tx] = W[(size_t)(k0 + ty + j * 8) * N + n0 + tx];
        __syncthreads();
#pragma unroll
        for (int j = 0; j < 4; j++)
            Wt[(size_t)(n0 + ty + j * 8) * K + k0 + tx] = f2bf(tile[tx][ty + j * 8]);
    } else {
        if (t < 4) acc[t] = 0.f;
        colsum[t] = 0.f;
    }
}

// ---------------- parallel CSR scan (3 small dispatches) + scatter ----------
// Measured fastest scan variant (r2: 318.4us wall). The single-1024-thread-
// block variant (r3/r4) is +8us: counts[t*20+j] loads are 80B-strided
// (uncoalesced) and everything serializes on one CU.
#define SCAN_B 32

__global__ void k_scan1(const int* __restrict__ counts, int* __restrict__ bsum) {
    __shared__ int sm[256];
    int t = threadIdx.x, b = blockIdx.x;
    int i0 = (b * 256 + t) * 3;
    int s = 0;
#pragma unroll
    for (int j = 0; j < 3; j++) { int i = i0 + j; if (i < NODES) s += counts[i]; }
    sm[t] = s;
    __syncthreads();
    int v = s;
#pragma unroll
    for (int o = 1; o < 256; o <<= 1) {
        int add = (t >= o) ? sm[t - o] : 0;
        __syncthreads();
        v += add;
        sm[t] = v;
        __syncthreads();
    }
    if (t == 255) bsum[b] = v;
}

// 1 wave: scan the 32 block sums -> exclusive bases; write offs[NODES]=total
__global__ void k_scan2(int* __restrict__ bsum, int* __restrict__ offs) {
    int t = threadIdx.x;                     // 64 threads = 1 wave
    int v = (t < SCAN_B) ? bsum[t] : 0;
    int x = v;
#pragma unroll
    for (int o = 1; o < 64; o <<= 1) {
        int y = __shfl_up(x, o);
        if (t >= o) x += y;
    }
    if (t < SCAN_B) bsum[t] = x - v;         // exclusive base
    if (t == SCAN_B - 1) offs[NODES] = x;    // grand total
}

__global__ void k_scan3(const int* __restrict__ counts, const int* __restrict__ bsum,
                        int* __restrict__ offs) {
    __shared__ int sm[256];
    int t = threadIdx.x, b = blockIdx.x;
    int i0 = (b * 256 + t) * 3;
    int c[3]; int s = 0;
#pragma unroll
    for (int j = 0; j < 3; j++) {
        int i = i0 + j;
        c[j] = (i < NODES) ? counts[i] : 0;
        s += c[j];
    }
    sm[t] = s;
    __syncthreads();
    int v = s;
#pragma unroll
    for (int o = 1; o < 256; o <<= 1) {
        int add = (t >= o) ? sm[t - o] : 0;
        __syncthreads();
        v += add;
        sm[t] = v;
        __syncthreads();
    }
    int run = bsum[b] + (v - s);             // block base + thread-exclusive
#pragma unroll
    for (int j = 0; j < 3; j++) {
        int i = i0 + j;
        if (i < NODES) { offs[i] = run; run += c[j]; }
    }
}

__global__ void k_scatter(const int* __restrict__ src, const int* __restrict__ dst,
                          const int* __restrict__ offs, int* __restrict__ cursor,
                          int* __restrict__ csr_src) {
    int e = blockIdx.x * blockDim.x + threadIdx.x;
    if (e < EDGES) {
        int d = dst[e];
        int pos = atomicAdd(&cursor[d], 1);
        csr_src[offs[d] + pos] = src[e];
    }
}

// ------- per-channel softmax aggregation, un-stabilized (inputs bounded) -----
// S waves per node (interleaved waveg%S — measured fastest agg variant, r10).
// Wave-uniform CSR walk via readfirstlane: csr[k] -> s_load; vector pipe:
// loop-invariant-offset gather + packed-f32 exp2/fma.
// Measured floor ~44.5us (layer 2): 11 structural variants land 44-50us
// (incl. XCD-pinned channel slicing: fetch 133->60MB but time +2us — the
// kernel is issue/latency-bound, NOT fetch-bound; keep this config).
template <int C, int S, int UNR>
__global__ void k_agg(const unsigned short* __restrict__ xb, const float* __restrict__ tt,
                      const int* __restrict__ offs, const int* __restrict__ csr,
                      unsigned short* __restrict__ out) {
    constexpr int CS  = C / S;
    constexpr int VPL = CS / 64;
    constexpr int W   = VPL / 2;
    typedef unsigned int uv __attribute__((ext_vector_type(W)));
    typedef unsigned short usv __attribute__((ext_vector_type(VPL)));
    int waveg = (int)((blockIdx.x * (unsigned)blockDim.x + threadIdx.x) >> 6);
    int lane = threadIdx.x & 63;
    int node = waveg / S;
    int slice = waveg % S;
    if (node >= NODES) return;
    int beg = __builtin_amdgcn_readfirstlane(offs[node]);
    int end = __builtin_amdgcn_readfirstlane(offs[node + 1]);
    int cb = slice * CS + lane * VPL;
    const unsigned short* __restrict__ xcb = xb + cb;
    f2 tl[W], l[W], s[W];
#pragma unroll
    for (int i = 0; i < W; i++) {
        tl[i][0] = tt[cb + 2 * i] * LOG2E;
        tl[i][1] = tt[cb + 2 * i + 1] * LOG2E;
        l[i][0] = 0.f; l[i][1] = 0.f;
        s[i][0] = 0.f; s[i][1] = 0.f;
    }
    int k = beg;
    for (; k + UNR <= end; k += UNR) {
        uv v[UNR];
#pragma unroll
        for (int u = 0; u < UNR; u++) {
            int sn = csr[k + u];                     // uniform -> s_load
            v[u] = *(const uv*)(xcb + (size_t)sn * C);
        }
#pragma unroll
        for (int u = 0; u < UNR; u++)
#pragma unroll
            for (int i = 0; i < W; i++) {
                unsigned wd = v[u][i];
                f2 xv;
                xv[0] = __uint_as_float(wd << 16);
                xv[1] = __uint_as_float(wd & 0xffff0000u);
                f2 a = xv * tl[i];
                f2 p;
                p[0] = __builtin_amdgcn_exp2f(a[0]);
                p[1] = __builtin_amdgcn_exp2f(a[1]);
                l[i] += p;
                s[i] = __builtin_elementwise_fma(p, xv, s[i]);
            }
    }
    for (; k < end; k++) {
        int sn = csr[k];
        uv vv = *(const uv*)(xcb + (size_t)sn * C);
#pragma unroll
        for (int i = 0; i < W; i++) {
            unsigned wd = vv[i];
            f2 xv;
            xv[0] = __uint_as_float(wd << 16);
            xv[1] = __uint_as_float(wd & 0xffff0000u);
            f2 a = xv * tl[i];
            f2 p;
            p[0] = __builtin_amdgcn_exp2f(a[0]);
            p[1] = __builtin_amdgcn_exp2f(a[1]);
            l[i] += p;
            s[i] = __builtin_elementwise_fma(p, xv, s[i]);
        }
    }
    bool has = end > beg;
    usv o;
#pragma unroll
    for (int i = 0; i < W; i++) {
        o[2 * i]     = f2bf(has ? s[i][0] / l[i][0] : 0.f);
        o[2 * i + 1] = f2bf(has ? s[i][1] / l[i][1] : 0.f);
    }
    *(usv*)(out + (size_t)node * C + cb) = o;
}

// ---------------- dual bf16 MFMA GEMM: C = A1*B1t^T + A2*B2t^T + bias ---------
// Tile 128x128, DIRECT-TO-REGISTER fragments — NO LDS staging, NO K-loop
// barriers. Rationale (r5-r8 ledger): six LDS-staged variants (2-barrier,
// dbuf, pair-64, slab-128, reg-staged, TM=64) ALL land 44-51us with MfmaUtil
// 7-8% — the block-wide barrier+drain structure itself is the floor (HIP
// emits vmcnt(0)+lgkmcnt(0) at every __syncthreads). LDS only gave 2x read
// amplification here; operands are L2-resident (weights 256-512KB, A fetch
// 12MB << logical). Per-lane fragment load = 16 rows x 64B = 16 FULLY
// consumed cache lines per instruction (same line count as coalesced 1KB),
// data mapping bit-identical to the old LDS path. Compiler now pipelines
// with counted vmcnt; waves never collectively parked.
// XCD-affinity swizzle: all NTILES n-variants of one m-tile share bx%8.
// LN sum/sumsq fused into epilogue (wave shfl-reduce, 1 barrier).
template <int K, int NT, int NTILES>
__global__ __launch_bounds__(256) void k_gemm_mfma(
    const unsigned short* __restrict__ A1, const unsigned short* __restrict__ B1t,
    const unsigned short* __restrict__ A2, const unsigned short* __restrict__ B2t,
    const float* __restrict__ bias, unsigned short* __restrict__ Co, int M,
    float* __restrict__ stat) {
    constexpr int TN = 128;
    __shared__ float rs[4], rq[4];

    // swizzled decode: bx = x + 8*(n + NTILES*mh); m = mh*8 + x
    int bx = blockIdx.x;
    int xid = bx & 7, q = bx >> 3;
    int n = q % NTILES, mh = q / NTILES;
    int m = mh * 8 + xid;
    if (m * 128 >= MPAD) return;           // pad tiles: whole block exits
    int m0 = m * 128, n0 = n * TN;

    int t = threadIdx.x;
    int wv = t >> 6, lane = t & 63;
    int wm = wv & 1, wn = wv >> 1;
    int lm = lane & 15, quad = lane >> 4;

    f32x4 acc[4][4] = {};

#pragma unroll
    for (int ph = 0; ph < 2; ph++) {
        const unsigned short* __restrict__ A  = ph ? A2 : A1;
        const unsigned short* __restrict__ Bt = ph ? B2t : B1t;
        // lane-fixed row bases: row = (half + i*16 + lm), k-off = quad*8
        const unsigned short* pa = A  + (size_t)(m0 + wm * 64 + lm) * K + quad * 8;
        const unsigned short* pb = Bt + (size_t)(n0 + wn * 64 + lm) * K + quad * 8;
#pragma unroll 2
        for (int kk = 0; kk < K; kk += 32) {
            bf16x8 af[4], bfr[4];
#pragma unroll
            for (int i = 0; i < 4; i++)
                af[i] = *(const bf16x8*)(pa + (size_t)(i * 16) * K + kk);
#pragma unroll
            for (int j = 0; j < 4; j++)
                bfr[j] = *(const bf16x8*)(pb + (size_t)(j * 16) * K + kk);
#pragma unroll
            for (int mi = 0; mi < 4; mi++)
#pragma unroll
                for (int nj = 0; nj < 4; nj++)
                    acc[mi][nj] = __builtin_amdgcn_mfma_f32_16x16x32_bf16(
                        af[mi], bfr[nj], acc[mi][nj], 0, 0, 0);
        }
    }

    float sum = 0.f, ss = 0.f;
#pragma unroll
    for (int mi = 0; mi < 4; mi++) {
        int rb = m0 + wm * 64 + mi * 16 + quad * 4;
#pragma unroll
        for (int nj = 0; nj < 4; nj++) {
            int col = n0 + wn * 64 + nj * 16 + lm;
            float bb = bias[col];
#pragma unroll
            for (int rg = 0; rg < 4; rg++) {
                int row = rb + rg;
                if (row < M) {
                    float y = acc[mi][nj][rg] + bb;
                    Co[(size_t)row * NT + col] = f2bf(y);
                    sum += y; ss += y * y;
                }
            }
        }
    }
    // wave shfl-reduce, then 1 barrier + single atomic pair per block
#pragma unroll
    for (int o = 32; o > 0; o >>= 1) {
        sum += __shfl_xor(sum, o);
        ss  += __shfl_xor(ss, o);
    }
    if (lane == 0) { rs[wv] = sum; rq[wv] = ss; }
    __syncthreads();
    if (t == 0) {
        float a0 = 0.f, a1 = 0.f;
#pragma unroll
        for (int i = 0; i < 4; i++) { a0 += rs[i]; a1 += rq[i]; }
        atomicAdd(&stat[0], a0); atomicAdd(&stat[1], a1);
    }
}

// ---------------- graph-LN + ReLU, in-place bf16, vectorized x8 --------------
template <int C>
__global__ void k_ln_relu_b(unsigned short* __restrict__ h, int n,
                            const float* __restrict__ st,
                            const float* __restrict__ g, const float* __restrict__ b) {
    typedef unsigned short us8 __attribute__((ext_vector_type(8)));
    float mu = st[0] / (float)n;
    float var = st[1] / (float)n - mu * mu;
    var = var < 0.f ? 0.f : var;
    float inv = 1.0f / (sqrtf(var) + EPSV);
    int i8 = (blockIdx.x * blockDim.x + threadIdx.x) * 8;
    if (i8 >= n) return;
    int c = i8 & (C - 1);
    us8 v = *(const us8*)(h + i8);
    us8 o;
#pragma unroll
    for (int j = 0; j < 8; j++) {
        float y = (bf2f(v[j]) - mu) * inv * g[c + j] + b[c + j];
        o[j] = f2bf(fmaxf(y, 0.f));
    }
    *(us8*)(h + i8) = o;
}

// graph-LN + ReLU + column-sum only (layer 2; h2 not needed afterwards)
__global__ void k_ln_colsum(const unsigned short* __restrict__ h, int n,
                            const float* __restrict__ st,
                            const float* __restrict__ g, const float* __restrict__ b,
                            float* __restrict__ colsum) {
    float mu = st[0] / (float)n;
    float var = st[1] / (float)n - mu * mu;
    var = var < 0.f ? 0.f : var;
    float inv = 1.0f / (sqrtf(var) + EPSV);
    int t = threadIdx.x;
    float gv = g[t], bv = b[t];
    float local = 0.f;
    int stride = gridDim.x * blockDim.x;   // multiple of 256 -> channel == t always
    for (int i = blockIdx.x * blockDim.x + t; i < n; i += stride) {
        float y = (bf2f(h[i]) - mu) * inv * gv + bv;
        local += fmaxf(y, 0.f);
    }
    atomicAdd(&colsum[t], local);
}

// ---------------- head: mean-pool @ Wf + bf -> LN(64) -> relu ----------------
// split-K matvec: 256 threads = 4 k-groups x 64 out-cols (coalesced Wf reads),
// LDS-reduce the 4 partials, then wave-wide LN on 64 lanes.
__global__ void k_final(const float* __restrict__ colsum, const float* __restrict__ Wf,
                        const float* __restrict__ bf, const float* __restrict__ gx,
                        const float* __restrict__ bx, float* __restrict__ out) {
    __shared__ float p[256];
    __shared__ float red[4][64];
    int t = threadIdx.x;
    p[t] = colsum[t] * (1.0f / (float)NODES);
    __syncthreads();
    int kg = t >> 6, o = t & 63;
    float a = 0.f;
#pragma unroll
    for (int j = 0; j < 64; j++) {
        int c = kg + j * 4;
        a = fmaf(p[c], Wf[c * 64 + o], a);
    }
    red[kg][o] = a;
    __syncthreads();
    if (t < 64) {
        float acc = bf[t] + red[0][t] + red[1][t] + red[2][t] + red[3][t];
        float sum = acc;
        for (int w = 32; w > 0; w >>= 1) sum += __shfl_xor(sum, w);
        float mu = sum * (1.0f / 64.0f);
        float d = acc - mu;
        float vs = d * d;
        for (int w = 32; w > 0; w >>= 1) vs += __shfl_xor(vs, w);
        float var = vs * (1.0f / 64.0f);
        float y = d * rsqrtf(var + EPSV) * gx[t] + bx[t];
        out[t] = fmaxf(y, 0.f);
    }
}

extern "C" void kernel_launch(void* const* d_in, const int* in_sizes, int n_in,
                              void* d_out, int out_size, void* d_ws, size_t ws_size,
                              hipStream_t stream) {
    const float* x   = (const float*)d_in[0];
    const int*   ei  = (const int*)d_in[1];
    const float* t1  = (const float*)d_in[2];
    const float* Wl1 = (const float*)d_in[3];
    const float* bl1 = (const float*)d_in[4];
    const float* Wr1 = (const float*)d_in[5];
    const float* g1  = (const float*)d_in[6];
    const float* be1 = (const float*)d_in[7];
    const float* t2  = (const float*)d_in[8];
    const float* Wl2 = (const float*)d_in[9];
    const float* bl2 = (const float*)d_in[10];
    const float* Wr2 = (const float*)d_in[11];
    const float* g2  = (const float*)d_in[12];
    const float* be2 = (const float*)d_in[13];
    const float* Wf  = (const float*)d_in[14];
    const float* bf  = (const float*)d_in[15];
    const float* gx  = (const float*)d_in[16];
    const float* bx  = (const float*)d_in[17];
    float* out = (float*)d_out;

    char* ws = (char*)d_ws;
    size_t off = 0;
    auto alloc = [&](size_t bytes) { size_t o = off; off = (off + bytes + 511) & ~511ull; return o; };
    size_t o_counts = alloc((size_t)NODES * 4);
    size_t o_cursor = alloc((size_t)NODES * 4);
    size_t zero_bytes = off;                         // memset: counts+cursor only
    size_t o_acc    = alloc(4 * 4);
    size_t o_colsum = alloc(256 * 4);
    size_t o_bsum = alloc((size_t)SCAN_B * 4);
    size_t o_offs = alloc((size_t)(NODES + 1) * 4);
    size_t o_csrc = alloc((size_t)EDGES * 4);
    size_t o_w1l  = alloc((size_t)512 * 256 * 2);
    size_t o_w1r  = alloc((size_t)512 * 256 * 2);
    size_t o_w2l  = alloc((size_t)256 * 512 * 2);
    size_t o_w2r  = alloc((size_t)256 * 512 * 2);
    size_t o_bufX = alloc((size_t)MPAD * 256 * 2);   // xb, later h2_pre (bf16)
    size_t o_agg  = alloc((size_t)MPAD * 512 * 2);   // agg1b / agg2b
    size_t o_h1   = alloc((size_t)(MPAD + 512) * 512 * 2); // h1 (+pad-tile slack)

    int*   counts = (int*)(ws + o_counts);
    int*   cursor = (int*)(ws + o_cursor);
    float* acc    = (float*)(ws + o_acc);      // [0,1]=L1 stats, [2,3]=L2 stats
    float* colsum = (float*)(ws + o_colsum);
    int*   bsum   = (int*)(ws + o_bsum);
    int*   offs   = (int*)(ws + o_offs);
    int*   csrc   = (int*)(ws + o_csrc);
    unsigned short* w1lt = (unsigned short*)(ws + o_w1l);
    unsigned short* w1rt = (unsigned short*)(ws + o_w1r);
    unsigned short* w2lt = (unsigned short*)(ws + o_w2l);
    unsigned short* w2rt = (unsigned short*)(ws + o_w2r);
    unsigned short* xb   = (unsigned short*)(ws + o_bufX);
    unsigned short* h2p  = (unsigned short*)(ws + o_bufX);  // reuse after xb dead
    unsigned short* aggb = (unsigned short*)(ws + o_agg);
    unsigned short* h1   = (unsigned short*)(ws + o_h1);

    const int* src = ei;
    const int* dst = ei + EDGES;

    hipMemsetAsync(ws, 0, zero_bytes, stream);

    // D1: fused prep (count + cast + transposes + zero acc/colsum)
    k_prep<<<PREP_TOTAL, 256, 0, stream>>>(dst, counts, x, xb,
                                           Wl1, Wr1, Wl2, Wr2,
                                           w1lt, w1rt, w2lt, w2rt,
                                           acc, colsum);
    // D2-D4: parallel CSR scan, then scatter
    k_scan1<<<SCAN_B, 256, 0, stream>>>(counts, bsum);
    k_scan2<<<1, 64, 0, stream>>>(bsum, offs);
    k_scan3<<<SCAN_B, 256, 0, stream>>>(counts, bsum, offs);
    k_scatter<<<(EDGES + 255) / 256, 256, 0, stream>>>(src, dst, offs, cursor, csrc);

    // ----- layer 1 -----  (2 waves per node, 128 ch each)
    k_agg<256, 2, 8><<<(NODES * 2 + 3) / 4, 256, 0, stream>>>(xb, t1, offs, csrc, aggb);
    k_gemm_mfma<256, 512, 4><<<8 * 4 * 20, 256, 0, stream>>>(
        aggb, w1lt, xb, w1rt, bl1, h1, NODES, acc);
    k_ln_relu_b<512><<<NODES * 512 / 8 / 256, 256, 0, stream>>>(h1, NODES * 512, acc, g1, be1);

    // ----- layer 2 -----  (2 waves per node, 256 ch each)
    k_agg<512, 2, 4><<<(NODES * 2 + 3) / 4, 256, 0, stream>>>(h1, t2, offs, csrc, aggb);
    k_gemm_mfma<512, 256, 2><<<8 * 2 * 20, 256, 0, stream>>>(
        aggb, w2lt, h1, w2rt, bl2, h2p, NODES, acc + 2);

    // ----- LN2 + colsum, then head -----
    k_ln_colsum<<<1024, 256, 0, stream>>>(h2p, NODES * 256, acc + 2, g2, be2, colsum);
    k_final<<<1, 256, 0, stream>>>(colsum, Wf, bf, gx, bx, out);
}

// Round 10
// 353.512 us; speedup vs baseline: 1.0824x; 1.0824x over previous
//
#include <hip/hip_runtime.h>
#include <math.h>

#define NODES 20000
#define MPAD  20096          // NODES padded to multiple of 128 (GEMM M-tiles)
#define EDGES 320000
#define EPSV  1e-5f
#define LOG2E 1.4426950408889634f

// k_prep block ranges
#define PREP_CNT   1250                    // count: 1250*256 >= EDGES
#define PREP_CAST  5000                    // cast: NODES*256/4/256
#define PREP_TR    512                     // 4 matrices * 128 tiles
#define PREP_TOTAL (PREP_CNT + PREP_CAST + PREP_TR + 1)

typedef short bf16x8 __attribute__((ext_vector_type(8)));
typedef float f32x4  __attribute__((ext_vector_type(4)));
typedef float f2     __attribute__((ext_vector_type(2)));

__device__ __forceinline__ unsigned short f2bf(float f) {
    unsigned int u = __float_as_uint(f);
    u = (u + 0x7fffu + ((u >> 16) & 1u)) >> 16;
    return (unsigned short)u;
}
__device__ __forceinline__ float bf2f(unsigned short h) {
    return __uint_as_float(((unsigned int)h) << 16);
}

// ---------------- fused prep: edge-count + x cast + 4x weight transpose + zeros
__global__ void k_prep(const int* __restrict__ dst, int* __restrict__ counts,
                       const float* __restrict__ x, unsigned short* __restrict__ xb,
                       const float* __restrict__ Wl1, const float* __restrict__ Wr1,
                       const float* __restrict__ Wl2, const float* __restrict__ Wr2,
                       unsigned short* __restrict__ o1l, unsigned short* __restrict__ o1r,
                       unsigned short* __restrict__ o2l, unsigned short* __restrict__ o2r,
                       float* __restrict__ acc, float* __restrict__ colsum) {
    int b = blockIdx.x;
    int t = threadIdx.x;
    if (b < PREP_CNT) {
        int e = b * 256 + t;
        if (e < EDGES) atomicAdd(&counts[dst[e]], 1);
    } else if (b < PREP_CNT + PREP_CAST) {
        int i = ((b - PREP_CNT) * 256 + t) * 4;
        float4 v = *(const float4*)(x + i);
        xb[i + 0] = f2bf(v.x); xb[i + 1] = f2bf(v.y);
        xb[i + 2] = f2bf(v.z); xb[i + 3] = f2bf(v.w);
    } else if (b < PREP_CNT + PREP_CAST + PREP_TR) {
        __shared__ float tile[32][33];
        int zz = b - PREP_CNT - PREP_CAST;     // 0..511
        int z = zz >> 7;                        // matrix 0..3
        int idx = zz & 127;                     // tile within matrix
        const float* W = (z == 0) ? Wl1 : (z == 1) ? Wr1 : (z == 2) ? Wl2 : Wr2;
        unsigned short* Wt = (z == 0) ? o1l : (z == 1) ? o1r : (z == 2) ? o2l : o2r;
        int K = (z < 2) ? 256 : 512, N = (z < 2) ? 512 : 256;
        int nb = N / 32;
        int n0 = (idx % nb) * 32, k0 = (idx / nb) * 32;
        int tx = t & 31, ty = t >> 5;          // (32,8) layout
#pragma unroll
        for (int j = 0; j < 4; j++)
            tile[ty + j * 8][tx] = W[(size_t)(k0 + ty + j * 8) * N + n0 + tx];
        __syncthreads();
#pragma unroll
        for (int j = 0; j < 4; j++)
            Wt[(size_t)(n0 + ty + j * 8) * K + k0 + tx] = f2bf(tile[tx][ty + j * 8]);
    } else {
        if (t < 4) acc[t] = 0.f;
        colsum[t] = 0.f;
    }
}

// ---------------- fused CSR build: scan + scatter, ONE dispatch --------------
// 32 blocks (trivially co-resident on 256 CUs) with device-scope atomic
// barriers. Phase 1 = per-block count scan (r2's measured-best layout);
// each block then redundantly computes its base from bsum[0..b) (32 ints)
// -> only 2 grid barriers. Phase 3 = grid-stride scatter (8192 thr x 40
// edges, independent iterations give atomic ILP). Replaces 4 dispatches.
#define CSR_B 32

__device__ __forceinline__ void grid_bar(int* ctr, int nblk) {
    __threadfence();                       // my writes visible device-wide
    __syncthreads();                       // whole block fenced
    if (threadIdx.x == 0) {
        __hip_atomic_fetch_add(ctr, 1, __ATOMIC_RELEASE, __HIP_MEMORY_SCOPE_AGENT);
        while (__hip_atomic_load(ctr, __ATOMIC_ACQUIRE, __HIP_MEMORY_SCOPE_AGENT) < nblk) {}
    }
    __syncthreads();                       // block released after arrival
}

__global__ __launch_bounds__(256) void k_csr(
    const int* __restrict__ counts, int* __restrict__ bsum, int* __restrict__ offs,
    const int* __restrict__ src, const int* __restrict__ dst,
    int* __restrict__ cursor, int* __restrict__ csr_src, int* __restrict__ bar) {
    __shared__ int sm[256];
    int t = threadIdx.x, b = blockIdx.x;
    // ---- phase 1: per-block scan of counts (3 nodes/thread, coalesced) ----
    int i0 = (b * 256 + t) * 3;
    int c[3]; int s = 0;
#pragma unroll
    for (int j = 0; j < 3; j++) {
        int i = i0 + j;
        c[j] = (i < NODES) ? counts[i] : 0;
        s += c[j];
    }
    sm[t] = s;
    __syncthreads();
    int v = s;
#pragma unroll
    for (int o = 1; o < 256; o <<= 1) {
        int add = (t >= o) ? sm[t - o] : 0;
        __syncthreads();
        v += add;
        sm[t] = v;
        __syncthreads();
    }
    if (t == 255) bsum[b] = v;             // block total
    grid_bar(&bar[0], CSR_B);
    // ---- phase 2: redundant per-block base + write offs ----
    int base = 0;
    for (int i = 0; i < b; i++) base += bsum[i];
    if (b == CSR_B - 1 && t == 255) offs[NODES] = base + v;
    int run = base + (v - s);              // exclusive prefix for this thread
#pragma unroll
    for (int j = 0; j < 3; j++) {
        int i = i0 + j;
        if (i < NODES) { offs[i] = run; run += c[j]; }
    }
    grid_bar(&bar[1], CSR_B);
    // ---- phase 3: scatter (grid-stride over edges) ----
    for (int e = b * 256 + t; e < EDGES; e += CSR_B * 256) {
        int d = dst[e];
        int pos = atomicAdd(&cursor[d], 1);
        csr_src[offs[d] + pos] = src[e];
    }
}

// ------- per-channel softmax aggregation, un-stabilized (inputs bounded) -----
// S waves per node (interleaved waveg%S — measured fastest agg variant, r10).
// Wave-uniform CSR walk via readfirstlane: csr[k] -> s_load; vector pipe:
// loop-invariant-offset gather + packed-f32 exp2/fma.
// Measured floor ~44.5us (layer 2): 11 structural variants land 44-50us
// (incl. XCD-pinned channel slicing: fetch 133->60MB but time +2us — the
// kernel is issue/latency-bound, NOT fetch-bound; keep this config).
template <int C, int S, int UNR>
__global__ void k_agg(const unsigned short* __restrict__ xb, const float* __restrict__ tt,
                      const int* __restrict__ offs, const int* __restrict__ csr,
                      unsigned short* __restrict__ out) {
    constexpr int CS  = C / S;
    constexpr int VPL = CS / 64;
    constexpr int W   = VPL / 2;
    typedef unsigned int uv __attribute__((ext_vector_type(W)));
    typedef unsigned short usv __attribute__((ext_vector_type(VPL)));
    int waveg = (int)((blockIdx.x * (unsigned)blockDim.x + threadIdx.x) >> 6);
    int lane = threadIdx.x & 63;
    int node = waveg / S;
    int slice = waveg % S;
    if (node >= NODES) return;
    int beg = __builtin_amdgcn_readfirstlane(offs[node]);
    int end = __builtin_amdgcn_readfirstlane(offs[node + 1]);
    int cb = slice * CS + lane * VPL;
    const unsigned short* __restrict__ xcb = xb + cb;
    f2 tl[W], l[W], s[W];
#pragma unroll
    for (int i = 0; i < W; i++) {
        tl[i][0] = tt[cb + 2 * i] * LOG2E;
        tl[i][1] = tt[cb + 2 * i + 1] * LOG2E;
        l[i][0] = 0.f; l[i][1] = 0.f;
        s[i][0] = 0.f; s[i][1] = 0.f;
    }
    int k = beg;
    for (; k + UNR <= end; k += UNR) {
        uv v[UNR];
#pragma unroll
        for (int u = 0; u < UNR; u++) {
            int sn = csr[k + u];                     // uniform -> s_load
            v[u] = *(const uv*)(xcb + (size_t)sn * C);
        }
#pragma unroll
        for (int u = 0; u < UNR; u++)
#pragma unroll
            for (int i = 0; i < W; i++) {
                unsigned wd = v[u][i];
                f2 xv;
                xv[0] = __uint_as_float(wd << 16);
                xv[1] = __uint_as_float(wd & 0xffff0000u);
                f2 a = xv * tl[i];
                f2 p;
                p[0] = __builtin_amdgcn_exp2f(a[0]);
                p[1] = __builtin_amdgcn_exp2f(a[1]);
                l[i] += p;
                s[i] = __builtin_elementwise_fma(p, xv, s[i]);
            }
    }
    for (; k < end; k++) {
        int sn = csr[k];
        uv vv = *(const uv*)(xcb + (size_t)sn * C);
#pragma unroll
        for (int i = 0; i < W; i++) {
            unsigned wd = vv[i];
            f2 xv;
            xv[0] = __uint_as_float(wd << 16);
            xv[1] = __uint_as_float(wd & 0xffff0000u);
            f2 a = xv * tl[i];
            f2 p;
            p[0] = __builtin_amdgcn_exp2f(a[0]);
            p[1] = __builtin_amdgcn_exp2f(a[1]);
            l[i] += p;
            s[i] = __builtin_elementwise_fma(p, xv, s[i]);
        }
    }
    bool has = end > beg;
    usv o;
#pragma unroll
    for (int i = 0; i < W; i++) {
        o[2 * i]     = f2bf(has ? s[i][0] / l[i][0] : 0.f);
        o[2 * i + 1] = f2bf(has ? s[i][1] / l[i][1] : 0.f);
    }
    *(usv*)(out + (size_t)node * C + cb) = o;
}

// ---------------- dual bf16 MFMA GEMM: C = A1*B1t^T + A2*B2t^T + bias ---------
// r7 reg-staged pipeline RESTORED VERBATIM (best measured wall, 315.4us).
// GEMM ledger (7 variants): 2-barrier 44.5 / dbuf +7.5 / pair-64 ~45 /
// slab-128 44.5 / reg-staged 45-47 (best wall) / TM=64 51 / direct-reg 72.
// The ~45us floor is robust vs staging mechanism, drain count, TLP, and
// no-LDS — do not restructure further from HIP source.
// Epilogue fixed: rs[4] (4 waves), was rs[8] summing uninitialized LDS.
template <int K, int NT, int NTILES, int TN>
__global__ __launch_bounds__(256) void k_gemm_mfma(
    const unsigned short* __restrict__ A1, const unsigned short* __restrict__ B1t,
    const unsigned short* __restrict__ A2, const unsigned short* __restrict__ B2t,
    const float* __restrict__ bias, unsigned short* __restrict__ Co, int M,
    float* __restrict__ stat) {
    constexpr int NF  = TN / 32;           // n-frags per wave (2 waves span TN)
    constexpr int BIT = TN / 64;           // B row-groups per chunk
    constexpr int HS  = K / 64;            // slabs per phase
    constexpr int NS  = 2 * HS;            // total slabs (both phases)
    __shared__ short As[2 * 128 * 32];     // 2 k-chunks, [128][32] each
    __shared__ short Bs[2 * TN * 32];
    __shared__ float rs[4], rq[4];

    // swizzled decode: bx = x + 8*(n + NTILES*mh); m = mh*8 + x
    int bx = blockIdx.x;
    int xid = bx & 7, q = bx >> 3;
    int n = q % NTILES, mh = q / NTILES;
    int m = mh * 8 + xid;
    if (m * 128 >= MPAD) return;           // pad tiles: whole block exits
    int m0 = m * 128, n0 = n * TN;

    int t = threadIdx.x;
    int wv = t >> 6, lane = t & 63;
    int wm = wv & 1, wn = wv >> 1;
    int lm = lane & 15, quad = lane >> 4;
    int sr = t >> 2;
    int sc8 = (t & 3) * 8;

    f32x4 acc[4][NF] = {};
    bf16x8 rA[2][2];                       // [chunk][rowgroup] prefetch regs
    bf16x8 rB[2][BIT];

    auto loadslab = [&](int s) {
        const unsigned short* __restrict__ A  = (s < HS) ? A1 : A2;
        const unsigned short* __restrict__ Bt = (s < HS) ? B1t : B2t;
        int kk = (s & (HS - 1)) * 64;
#pragma unroll
        for (int c = 0; c < 2; c++) {
#pragma unroll
            for (int it = 0; it < 2; it++)
                rA[c][it] = *(const bf16x8*)(A + (size_t)(m0 + it * 64 + sr) * K + kk + c * 32 + sc8);
#pragma unroll
            for (int it = 0; it < BIT; it++)
                rB[c][it] = *(const bf16x8*)(Bt + (size_t)(n0 + it * 64 + sr) * K + kk + c * 32 + sc8);
        }
    };

    loadslab(0);
    for (int s = 0; s < NS; s++) {
        if (s) __syncthreads();            // all waves done reading LDS of s-1
#pragma unroll
        for (int c = 0; c < 2; c++) {      // regs -> LDS (vmcnt wait auto)
#pragma unroll
            for (int it = 0; it < 2; it++)
                *(bf16x8*)&As[c * 4096 + it * 2048 + t * 8] = rA[c][it];
#pragma unroll
            for (int it = 0; it < BIT; it++)
                *(bf16x8*)&Bs[c * (TN * 32) + it * 2048 + t * 8] = rB[c][it];
        }
        __syncthreads();                   // slab visible to all waves
        if (s + 1 < NS) loadslab(s + 1);   // prefetch flies under compute
#pragma unroll
        for (int c = 0; c < 2; c++) {
            bf16x8 af[4], bfr[NF];
#pragma unroll
            for (int i = 0; i < 4; i++)
                af[i] = *(const bf16x8*)&As[c * 4096 + (wm * 64 + i * 16 + lm) * 32 + quad * 8];
#pragma unroll
            for (int j = 0; j < NF; j++)
                bfr[j] = *(const bf16x8*)&Bs[c * (TN * 32) + (wn * (TN / 2) + j * 16 + lm) * 32 + quad * 8];
#pragma unroll
            for (int mi = 0; mi < 4; mi++)
#pragma unroll
                for (int nj = 0; nj < NF; nj++)
                    acc[mi][nj] = __builtin_amdgcn_mfma_f32_16x16x32_bf16(
                        af[mi], bfr[nj], acc[mi][nj], 0, 0, 0);
        }
    }

    float sum = 0.f, ss = 0.f;
#pragma unroll
    for (int mi = 0; mi < 4; mi++) {
        int rb = m0 + wm * 64 + mi * 16 + quad * 4;
#pragma unroll
        for (int nj = 0; nj < NF; nj++) {
            int col = n0 + wn * (TN / 2) + nj * 16 + lm;
            float bb = bias[col];
#pragma unroll
            for (int rg = 0; rg < 4; rg++) {
                int row = rb + rg;
                if (row < M) {
                    float y = acc[mi][nj][rg] + bb;
                    Co[(size_t)row * NT + col] = f2bf(y);
                    sum += y; ss += y * y;
                }
            }
        }
    }
    // wave shfl-reduce, then 1 barrier + single atomic pair per block
#pragma unroll
    for (int o = 32; o > 0; o >>= 1) {
        sum += __shfl_xor(sum, o);
        ss  += __shfl_xor(ss, o);
    }
    if (lane == 0) { rs[wv] = sum; rq[wv] = ss; }
    __syncthreads();
    if (t == 0) {
        float a0 = 0.f, a1 = 0.f;
#pragma unroll
        for (int i = 0; i < 4; i++) { a0 += rs[i]; a1 += rq[i]; }
        atomicAdd(&stat[0], a0); atomicAdd(&stat[1], a1);
    }
}

// ---------------- graph-LN + ReLU, in-place bf16, vectorized x8 --------------
template <int C>
__global__ void k_ln_relu_b(unsigned short* __restrict__ h, int n,
                            const float* __restrict__ st,
                            const float* __restrict__ g, const float* __restrict__ b) {
    typedef unsigned short us8 __attribute__((ext_vector_type(8)));
    float mu = st[0] / (float)n;
    float var = st[1] / (float)n - mu * mu;
    var = var < 0.f ? 0.f : var;
    float inv = 1.0f / (sqrtf(var) + EPSV);
    int i8 = (blockIdx.x * blockDim.x + threadIdx.x) * 8;
    if (i8 >= n) return;
    int c = i8 & (C - 1);
    us8 v = *(const us8*)(h + i8);
    us8 o;
#pragma unroll
    for (int j = 0; j < 8; j++) {
        float y = (bf2f(v[j]) - mu) * inv * g[c + j] + b[c + j];
        o[j] = f2bf(fmaxf(y, 0.f));
    }
    *(us8*)(h + i8) = o;
}

// ------- fused: graph-LN2 + ReLU + column-sum, then head (one dispatch) ------
// 256 blocks (1/CU, co-resident) grid-stride colsum; device barrier; block 0
// runs the mean-pool @ Wf -> LN(64) -> relu head. Replaces 2 dispatches.
__global__ __launch_bounds__(256) void k_lncol_final(
    const unsigned short* __restrict__ h, int n, const float* __restrict__ st,
    const float* __restrict__ g, const float* __restrict__ b,
    float* __restrict__ colsum, const float* __restrict__ Wf,
    const float* __restrict__ bf, const float* __restrict__ gx,
    const float* __restrict__ bx, float* __restrict__ out, int* __restrict__ bar) {
    __shared__ float p[256];
    __shared__ float red[4][64];
    float mu = st[0] / (float)n;
    float var = st[1] / (float)n - mu * mu;
    var = var < 0.f ? 0.f : var;
    float inv = 1.0f / (sqrtf(var) + EPSV);
    int t = threadIdx.x;
    float gv = g[t], bv = b[t];
    float local = 0.f;
    int stride = gridDim.x * blockDim.x;   // multiple of 256 -> channel == t always
    for (int i = blockIdx.x * blockDim.x + t; i < n; i += stride) {
        float y = (bf2f(h[i]) - mu) * inv * gv + bv;
        local += fmaxf(y, 0.f);
    }
    atomicAdd(&colsum[t], local);
    __threadfence();
    __syncthreads();
    if (t == 0)
        __hip_atomic_fetch_add(&bar[2], 1, __ATOMIC_RELEASE, __HIP_MEMORY_SCOPE_AGENT);
    if (blockIdx.x != 0) return;
    if (t == 0)
        while (__hip_atomic_load(&bar[2], __ATOMIC_ACQUIRE, __HIP_MEMORY_SCOPE_AGENT) < (int)gridDim.x) {}
    __syncthreads();
    // ---- head: split-K matvec (4 k-groups x 64 cols) + wave LN ----
    p[t] = colsum[t] * (1.0f / (float)NODES);
    __syncthreads();
    int kg = t >> 6, o = t & 63;
    float a = 0.f;
#pragma unroll
    for (int j = 0; j < 64; j++) {
        int c = kg + j * 4;
        a = fmaf(p[c], Wf[c * 64 + o], a);
    }
    red[kg][o] = a;
    __syncthreads();
    if (t < 64) {
        float acc = bf[t] + red[0][t] + red[1][t] + red[2][t] + red[3][t];
        float sum = acc;
        for (int w = 32; w > 0; w >>= 1) sum += __shfl_xor(sum, w);
        float muh = sum * (1.0f / 64.0f);
        float d = acc - muh;
        float vs = d * d;
        for (int w = 32; w > 0; w >>= 1) vs += __shfl_xor(vs, w);
        float varh = vs * (1.0f / 64.0f);
        float y = d * rsqrtf(varh + EPSV) * gx[t] + bx[t];
        out[t] = fmaxf(y, 0.f);
    }
}

extern "C" void kernel_launch(void* const* d_in, const int* in_sizes, int n_in,
                              void* d_out, int out_size, void* d_ws, size_t ws_size,
                              hipStream_t stream) {
    const float* x   = (const float*)d_in[0];
    const int*   ei  = (const int*)d_in[1];
    const float* t1  = (const float*)d_in[2];
    const float* Wl1 = (const float*)d_in[3];
    const float* bl1 = (const float*)d_in[4];
    const float* Wr1 = (const float*)d_in[5];
    const float* g1  = (const float*)d_in[6];
    const float* be1 = (const float*)d_in[7];
    const float* t2  = (const float*)d_in[8];
    const float* Wl2 = (const float*)d_in[9];
    const float* bl2 = (const float*)d_in[10];
    const float* Wr2 = (const float*)d_in[11];
    const float* g2  = (const float*)d_in[12];
    const float* be2 = (const float*)d_in[13];
    const float* Wf  = (const float*)d_in[14];
    const float* bf  = (const float*)d_in[15];
    const float* gx  = (const float*)d_in[16];
    const float* bx  = (const float*)d_in[17];
    float* out = (float*)d_out;

    char* ws = (char*)d_ws;
    size_t off = 0;
    auto alloc = [&](size_t bytes) { size_t o = off; off = (off + bytes + 511) & ~511ull; return o; };
    size_t o_counts = alloc((size_t)NODES * 4);
    size_t o_cursor = alloc((size_t)NODES * 4);
    size_t o_bar    = alloc(16 * 4);                 // grid-barrier counters
    size_t zero_bytes = off;                         // memset: counts+cursor+bar
    size_t o_acc    = alloc(4 * 4);
    size_t o_colsum = alloc(256 * 4);
    size_t o_bsum = alloc((size_t)CSR_B * 4);
    size_t o_offs = alloc((size_t)(NODES + 1) * 4);
    size_t o_csrc = alloc((size_t)EDGES * 4);
    size_t o_w1l  = alloc((size_t)512 * 256 * 2);
    size_t o_w1r  = alloc((size_t)512 * 256 * 2);
    size_t o_w2l  = alloc((size_t)256 * 512 * 2);
    size_t o_w2r  = alloc((size_t)256 * 512 * 2);
    size_t o_bufX = alloc((size_t)MPAD * 256 * 2);   // xb, later h2_pre (bf16)
    size_t o_agg  = alloc((size_t)MPAD * 512 * 2);   // agg1b / agg2b
    size_t o_h1   = alloc((size_t)(MPAD + 512) * 512 * 2); // h1 (+pad-tile slack)

    int*   counts = (int*)(ws + o_counts);
    int*   cursor = (int*)(ws + o_cursor);
    int*   bar    = (int*)(ws + o_bar);
    float* acc    = (float*)(ws + o_acc);      // [0,1]=L1 stats, [2,3]=L2 stats
    float* colsum = (float*)(ws + o_colsum);
    int*   bsum   = (int*)(ws + o_bsum);
    int*   offs   = (int*)(ws + o_offs);
    int*   csrc   = (int*)(ws + o_csrc);
    unsigned short* w1lt = (unsigned short*)(ws + o_w1l);
    unsigned short* w1rt = (unsigned short*)(ws + o_w1r);
    unsigned short* w2lt = (unsigned short*)(ws + o_w2l);
    unsigned short* w2rt = (unsigned short*)(ws + o_w2r);
    unsigned short* xb   = (unsigned short*)(ws + o_bufX);
    unsigned short* h2p  = (unsigned short*)(ws + o_bufX);  // reuse after xb dead
    unsigned short* aggb = (unsigned short*)(ws + o_agg);
    unsigned short* h1   = (unsigned short*)(ws + o_h1);

    const int* src = ei;
    const int* dst = ei + EDGES;

    hipMemsetAsync(ws, 0, zero_bytes, stream);

    // D1: fused prep (count + cast + transposes + zero acc/colsum)
    k_prep<<<PREP_TOTAL, 256, 0, stream>>>(dst, counts, x, xb,
                                           Wl1, Wr1, Wl2, Wr2,
                                           w1lt, w1rt, w2lt, w2rt,
                                           acc, colsum);
    // D2: fused CSR build (scan + scatter, device barriers)
    k_csr<<<CSR_B, 256, 0, stream>>>(counts, bsum, offs, src, dst, cursor, csrc, bar);

    // ----- layer 1 -----  (2 waves per node, 128 ch each)
    k_agg<256, 2, 8><<<(NODES * 2 + 3) / 4, 256, 0, stream>>>(xb, t1, offs, csrc, aggb);
    k_gemm_mfma<256, 512, 4, 128><<<8 * 4 * 20, 256, 0, stream>>>(
        aggb, w1lt, xb, w1rt, bl1, h1, NODES, acc);
    k_ln_relu_b<512><<<NODES * 512 / 8 / 256, 256, 0, stream>>>(h1, NODES * 512, acc, g1, be1);

    // ----- layer 2 -----  (2 waves per node, 256 ch each)
    k_agg<512, 2, 4><<<(NODES * 2 + 3) / 4, 256, 0, stream>>>(h1, t2, offs, csrc, aggb);
    k_gemm_mfma<512, 256, 2, 128><<<8 * 2 * 20, 256, 0, stream>>>(
        aggb, w2lt, h1, w2rt, bl2, h2p, NODES, acc + 2);

    // ----- fused LN2 + colsum + head -----
    k_lncol_final<<<256, 256, 0, stream>>>(h2p, NODES * 256, acc + 2, g2, be2,
                                           colsum, Wf, bf, gx, bx, out, bar);
}

// Round 11
// 320.712 us; speedup vs baseline: 1.1931x; 1.1023x over previous
//
#include <hip/hip_runtime.h>
#include <math.h>

#define NODES 20000
#define MPAD  20096          // NODES padded to multiple of 128 (GEMM M-tiles)
#define EDGES 320000
#define EPSV  1e-5f
#define LOG2E 1.4426950408889634f

// k_prep block ranges
#define PREP_CNT   1250                    // count: 1250*256 >= EDGES
#define PREP_CAST  5000                    // cast: NODES*256/4/256
#define PREP_TR    512                     // 4 matrices * 128 tiles
#define PREP_TOTAL (PREP_CNT + PREP_CAST + PREP_TR + 1)

typedef short bf16x8 __attribute__((ext_vector_type(8)));
typedef float f32x4  __attribute__((ext_vector_type(4)));
typedef float f2     __attribute__((ext_vector_type(2)));

__device__ __forceinline__ unsigned short f2bf(float f) {
    unsigned int u = __float_as_uint(f);
    u = (u + 0x7fffu + ((u >> 16) & 1u)) >> 16;
    return (unsigned short)u;
}
__device__ __forceinline__ float bf2f(unsigned short h) {
    return __uint_as_float(((unsigned int)h) << 16);
}

// ---------------- fused prep: edge-count + x cast + 4x weight transpose + zeros
__global__ void k_prep(const int* __restrict__ dst, int* __restrict__ counts,
                       const float* __restrict__ x, unsigned short* __restrict__ xb,
                       const float* __restrict__ Wl1, const float* __restrict__ Wr1,
                       const float* __restrict__ Wl2, const float* __restrict__ Wr2,
                       unsigned short* __restrict__ o1l, unsigned short* __restrict__ o1r,
                       unsigned short* __restrict__ o2l, unsigned short* __restrict__ o2r,
                       float* __restrict__ acc, float* __restrict__ colsum) {
    int b = blockIdx.x;
    int t = threadIdx.x;
    if (b < PREP_CNT) {
        int e = b * 256 + t;
        if (e < EDGES) atomicAdd(&counts[dst[e]], 1);
    } else if (b < PREP_CNT + PREP_CAST) {
        int i = ((b - PREP_CNT) * 256 + t) * 4;
        float4 v = *(const float4*)(x + i);
        xb[i + 0] = f2bf(v.x); xb[i + 1] = f2bf(v.y);
        xb[i + 2] = f2bf(v.z); xb[i + 3] = f2bf(v.w);
    } else if (b < PREP_CNT + PREP_CAST + PREP_TR) {
        __shared__ float tile[32][33];
        int zz = b - PREP_CNT - PREP_CAST;     // 0..511
        int z = zz >> 7;                        // matrix 0..3
        int idx = zz & 127;                     // tile within matrix
        const float* W = (z == 0) ? Wl1 : (z == 1) ? Wr1 : (z == 2) ? Wl2 : Wr2;
        unsigned short* Wt = (z == 0) ? o1l : (z == 1) ? o1r : (z == 2) ? o2l : o2r;
        int K = (z < 2) ? 256 : 512, N = (z < 2) ? 512 : 256;
        int nb = N / 32;
        int n0 = (idx % nb) * 32, k0 = (idx / nb) * 32;
        int tx = t & 31, ty = t >> 5;          // (32,8) layout
#pragma unroll
        for (int j = 0; j < 4; j++)
            tile[ty + j * 8][tx] = W[(size_t)(k0 + ty + j * 8) * N + n0 + tx];
        __syncthreads();
#pragma unroll
        for (int j = 0; j < 4; j++)
            Wt[(size_t)(n0 + ty + j * 8) * K + k0 + tx] = f2bf(tile[tx][ty + j * 8]);
    } else {
        if (t < 4) acc[t] = 0.f;
        colsum[t] = 0.f;
    }
}

// ---------------- parallel CSR scan (3 small dispatches) + scatter ----------
// Measured-best chain (r2: 318.4 / r7: 315.4 walls). The r10 single-dispatch
// fused k_csr REGRESSED hard (59-64us): its 32-block grid starved the
// scatter phase (40 serialized atomic round-trips/thread, occupancy 1.2%).
// Keep scatter at 1250 blocks (1 edge/thread).
#define SCAN_B 32

__global__ void k_scan1(const int* __restrict__ counts, int* __restrict__ bsum) {
    __shared__ int sm[256];
    int t = threadIdx.x, b = blockIdx.x;
    int i0 = (b * 256 + t) * 3;
    int s = 0;
#pragma unroll
    for (int j = 0; j < 3; j++) { int i = i0 + j; if (i < NODES) s += counts[i]; }
    sm[t] = s;
    __syncthreads();
    int v = s;
#pragma unroll
    for (int o = 1; o < 256; o <<= 1) {
        int add = (t >= o) ? sm[t - o] : 0;
        __syncthreads();
        v += add;
        sm[t] = v;
        __syncthreads();
    }
    if (t == 255) bsum[b] = v;
}

// 1 wave: scan the 32 block sums -> exclusive bases; write offs[NODES]=total
__global__ void k_scan2(int* __restrict__ bsum, int* __restrict__ offs) {
    int t = threadIdx.x;                     // 64 threads = 1 wave
    int v = (t < SCAN_B) ? bsum[t] : 0;
    int x = v;
#pragma unroll
    for (int o = 1; o < 64; o <<= 1) {
        int y = __shfl_up(x, o);
        if (t >= o) x += y;
    }
    if (t < SCAN_B) bsum[t] = x - v;         // exclusive base
    if (t == SCAN_B - 1) offs[NODES] = x;    // grand total
}

__global__ void k_scan3(const int* __restrict__ counts, const int* __restrict__ bsum,
                        int* __restrict__ offs) {
    __shared__ int sm[256];
    int t = threadIdx.x, b = blockIdx.x;
    int i0 = (b * 256 + t) * 3;
    int c[3]; int s = 0;
#pragma unroll
    for (int j = 0; j < 3; j++) {
        int i = i0 + j;
        c[j] = (i < NODES) ? counts[i] : 0;
        s += c[j];
    }
    sm[t] = s;
    __syncthreads();
    int v = s;
#pragma unroll
    for (int o = 1; o < 256; o <<= 1) {
        int add = (t >= o) ? sm[t - o] : 0;
        __syncthreads();
        v += add;
        sm[t] = v;
        __syncthreads();
    }
    int run = bsum[b] + (v - s);             // block base + thread-exclusive
#pragma unroll
    for (int j = 0; j < 3; j++) {
        int i = i0 + j;
        if (i < NODES) { offs[i] = run; run += c[j]; }
    }
}

__global__ void k_scatter(const int* __restrict__ src, const int* __restrict__ dst,
                          const int* __restrict__ offs, int* __restrict__ cursor,
                          int* __restrict__ csr_src) {
    int e = blockIdx.x * blockDim.x + threadIdx.x;
    if (e < EDGES) {
        int d = dst[e];
        int pos = atomicAdd(&cursor[d], 1);
        csr_src[offs[d] + pos] = src[e];
    }
}

// ------- per-channel softmax aggregation, un-stabilized (inputs bounded) -----
// S waves per node (interleaved waveg%S — measured fastest agg variant, r10).
// Wave-uniform CSR walk via readfirstlane: csr[k] -> s_load; vector pipe:
// loop-invariant-offset gather + packed-f32 exp2/fma.
// Measured floor ~44.5us (layer 2): 11 structural variants land 44-50us
// (incl. XCD-pinned channel slicing: fetch 133->60MB but time +2us — the
// kernel is issue/latency-bound, NOT fetch-bound; keep this config).
template <int C, int S, int UNR>
__global__ void k_agg(const unsigned short* __restrict__ xb, const float* __restrict__ tt,
                      const int* __restrict__ offs, const int* __restrict__ csr,
                      unsigned short* __restrict__ out) {
    constexpr int CS  = C / S;
    constexpr int VPL = CS / 64;
    constexpr int W   = VPL / 2;
    typedef unsigned int uv __attribute__((ext_vector_type(W)));
    typedef unsigned short usv __attribute__((ext_vector_type(VPL)));
    int waveg = (int)((blockIdx.x * (unsigned)blockDim.x + threadIdx.x) >> 6);
    int lane = threadIdx.x & 63;
    int node = waveg / S;
    int slice = waveg % S;
    if (node >= NODES) return;
    int beg = __builtin_amdgcn_readfirstlane(offs[node]);
    int end = __builtin_amdgcn_readfirstlane(offs[node + 1]);
    int cb = slice * CS + lane * VPL;
    const unsigned short* __restrict__ xcb = xb + cb;
    f2 tl[W], l[W], s[W];
#pragma unroll
    for (int i = 0; i < W; i++) {
        tl[i][0] = tt[cb + 2 * i] * LOG2E;
        tl[i][1] = tt[cb + 2 * i + 1] * LOG2E;
        l[i][0] = 0.f; l[i][1] = 0.f;
        s[i][0] = 0.f; s[i][1] = 0.f;
    }
    int k = beg;
    for (; k + UNR <= end; k += UNR) {
        uv v[UNR];
#pragma unroll
        for (int u = 0; u < UNR; u++) {
            int sn = csr[k + u];                     // uniform -> s_load
            v[u] = *(const uv*)(xcb + (size_t)sn * C);
        }
#pragma unroll
        for (int u = 0; u < UNR; u++)
#pragma unroll
            for (int i = 0; i < W; i++) {
                unsigned wd = v[u][i];
                f2 xv;
                xv[0] = __uint_as_float(wd << 16);
                xv[1] = __uint_as_float(wd & 0xffff0000u);
                f2 a = xv * tl[i];
                f2 p;
                p[0] = __builtin_amdgcn_exp2f(a[0]);
                p[1] = __builtin_amdgcn_exp2f(a[1]);
                l[i] += p;
                s[i] = __builtin_elementwise_fma(p, xv, s[i]);
            }
    }
    for (; k < end; k++) {
        int sn = csr[k];
        uv vv = *(const uv*)(xcb + (size_t)sn * C);
#pragma unroll
        for (int i = 0; i < W; i++) {
            unsigned wd = vv[i];
            f2 xv;
            xv[0] = __uint_as_float(wd << 16);
            xv[1] = __uint_as_float(wd & 0xffff0000u);
            f2 a = xv * tl[i];
            f2 p;
            p[0] = __builtin_amdgcn_exp2f(a[0]);
            p[1] = __builtin_amdgcn_exp2f(a[1]);
            l[i] += p;
            s[i] = __builtin_elementwise_fma(p, xv, s[i]);
        }
    }
    bool has = end > beg;
    usv o;
#pragma unroll
    for (int i = 0; i < W; i++) {
        o[2 * i]     = f2bf(has ? s[i][0] / l[i][0] : 0.f);
        o[2 * i + 1] = f2bf(has ? s[i][1] / l[i][1] : 0.f);
    }
    *(usv*)(out + (size_t)node * C + cb) = o;
}

// ---------------- dual bf16 MFMA GEMM: C = A1*B1t^T + A2*B2t^T + bias ---------
// r7 reg-staged pipeline (best measured wall config). GEMM ledger (7
// variants): 2-barrier 44.5 / dbuf +7.5 / pair-64 ~45 / slab-128 44.5 /
// reg-staged 45-47 (best wall) / TM=64 51 / direct-reg 72. The ~45us floor
// is robust vs staging mechanism, drain count, TLP, and no-LDS — do not
// restructure further from HIP source.
// Epilogue: rs[4] (4 waves) — fixed from the r7 rs[8] latent bug.
template <int K, int NT, int NTILES, int TN>
__global__ __launch_bounds__(256) void k_gemm_mfma(
    const unsigned short* __restrict__ A1, const unsigned short* __restrict__ B1t,
    const unsigned short* __restrict__ A2, const unsigned short* __restrict__ B2t,
    const float* __restrict__ bias, unsigned short* __restrict__ Co, int M,
    float* __restrict__ stat) {
    constexpr int NF  = TN / 32;           // n-frags per wave (2 waves span TN)
    constexpr int BIT = TN / 64;           // B row-groups per chunk
    constexpr int HS  = K / 64;            // slabs per phase
    constexpr int NS  = 2 * HS;            // total slabs (both phases)
    __shared__ short As[2 * 128 * 32];     // 2 k-chunks, [128][32] each
    __shared__ short Bs[2 * TN * 32];
    __shared__ float rs[4], rq[4];

    // swizzled decode: bx = x + 8*(n + NTILES*mh); m = mh*8 + x
    int bx = blockIdx.x;
    int xid = bx & 7, q = bx >> 3;
    int n = q % NTILES, mh = q / NTILES;
    int m = mh * 8 + xid;
    if (m * 128 >= MPAD) return;           // pad tiles: whole block exits
    int m0 = m * 128, n0 = n * TN;

    int t = threadIdx.x;
    int wv = t >> 6, lane = t & 63;
    int wm = wv & 1, wn = wv >> 1;
    int lm = lane & 15, quad = lane >> 4;
    int sr = t >> 2;
    int sc8 = (t & 3) * 8;

    f32x4 acc[4][NF] = {};
    bf16x8 rA[2][2];                       // [chunk][rowgroup] prefetch regs
    bf16x8 rB[2][BIT];

    auto loadslab = [&](int s) {
        const unsigned short* __restrict__ A  = (s < HS) ? A1 : A2;
        const unsigned short* __restrict__ Bt = (s < HS) ? B1t : B2t;
        int kk = (s & (HS - 1)) * 64;
#pragma unroll
        for (int c = 0; c < 2; c++) {
#pragma unroll
            for (int it = 0; it < 2; it++)
                rA[c][it] = *(const bf16x8*)(A + (size_t)(m0 + it * 64 + sr) * K + kk + c * 32 + sc8);
#pragma unroll
            for (int it = 0; it < BIT; it++)
                rB[c][it] = *(const bf16x8*)(Bt + (size_t)(n0 + it * 64 + sr) * K + kk + c * 32 + sc8);
        }
    };

    loadslab(0);
    for (int s = 0; s < NS; s++) {
        if (s) __syncthreads();            // all waves done reading LDS of s-1
#pragma unroll
        for (int c = 0; c < 2; c++) {      // regs -> LDS (vmcnt wait auto)
#pragma unroll
            for (int it = 0; it < 2; it++)
                *(bf16x8*)&As[c * 4096 + it * 2048 + t * 8] = rA[c][it];
#pragma unroll
            for (int it = 0; it < BIT; it++)
                *(bf16x8*)&Bs[c * (TN * 32) + it * 2048 + t * 8] = rB[c][it];
        }
        __syncthreads();                   // slab visible to all waves
        if (s + 1 < NS) loadslab(s + 1);   // prefetch flies under compute
#pragma unroll
        for (int c = 0; c < 2; c++) {
            bf16x8 af[4], bfr[NF];
#pragma unroll
            for (int i = 0; i < 4; i++)
                af[i] = *(const bf16x8*)&As[c * 4096 + (wm * 64 + i * 16 + lm) * 32 + quad * 8];
#pragma unroll
            for (int j = 0; j < NF; j++)
                bfr[j] = *(const bf16x8*)&Bs[c * (TN * 32) + (wn * (TN / 2) + j * 16 + lm) * 32 + quad * 8];
#pragma unroll
            for (int mi = 0; mi < 4; mi++)
#pragma unroll
                for (int nj = 0; nj < NF; nj++)
                    acc[mi][nj] = __builtin_amdgcn_mfma_f32_16x16x32_bf16(
                        af[mi], bfr[nj], acc[mi][nj], 0, 0, 0);
        }
    }

    float sum = 0.f, ss = 0.f;
#pragma unroll
    for (int mi = 0; mi < 4; mi++) {
        int rb = m0 + wm * 64 + mi * 16 + quad * 4;
#pragma unroll
        for (int nj = 0; nj < NF; nj++) {
            int col = n0 + wn * (TN / 2) + nj * 16 + lm;
            float bb = bias[col];
#pragma unroll
            for (int rg = 0; rg < 4; rg++) {
                int row = rb + rg;
                if (row < M) {
                    float y = acc[mi][nj][rg] + bb;
                    Co[(size_t)row * NT + col] = f2bf(y);
                    sum += y; ss += y * y;
                }
            }
        }
    }
    // wave shfl-reduce, then 1 barrier + single atomic pair per block
#pragma unroll
    for (int o = 32; o > 0; o >>= 1) {
        sum += __shfl_xor(sum, o);
        ss  += __shfl_xor(ss, o);
    }
    if (lane == 0) { rs[wv] = sum; rq[wv] = ss; }
    __syncthreads();
    if (t == 0) {
        float a0 = 0.f, a1 = 0.f;
#pragma unroll
        for (int i = 0; i < 4; i++) { a0 += rs[i]; a1 += rq[i]; }
        atomicAdd(&stat[0], a0); atomicAdd(&stat[1], a1);
    }
}

// ---------------- graph-LN + ReLU, in-place bf16, vectorized x8 --------------
template <int C>
__global__ void k_ln_relu_b(unsigned short* __restrict__ h, int n,
                            const float* __restrict__ st,
                            const float* __restrict__ g, const float* __restrict__ b) {
    typedef unsigned short us8 __attribute__((ext_vector_type(8)));
    float mu = st[0] / (float)n;
    float var = st[1] / (float)n - mu * mu;
    var = var < 0.f ? 0.f : var;
    float inv = 1.0f / (sqrtf(var) + EPSV);
    int i8 = (blockIdx.x * blockDim.x + threadIdx.x) * 8;
    if (i8 >= n) return;
    int c = i8 & (C - 1);
    us8 v = *(const us8*)(h + i8);
    us8 o;
#pragma unroll
    for (int j = 0; j < 8; j++) {
        float y = (bf2f(v[j]) - mu) * inv * g[c + j] + b[c + j];
        o[j] = f2bf(fmaxf(y, 0.f));
    }
    *(us8*)(h + i8) = o;
}

// ------- fused: graph-LN2 + ReLU + column-sum, then head (one dispatch) ------
// 256 blocks (1/CU, co-resident) grid-stride colsum; device barrier; block 0
// runs the mean-pool @ Wf -> LN(64) -> relu head. Replaces 2 dispatches.
// r10 wall arithmetic credits this fusion ~-12us (k_csr was the regression).
__global__ __launch_bounds__(256) void k_lncol_final(
    const unsigned short* __restrict__ h, int n, const float* __restrict__ st,
    const float* __restrict__ g, const float* __restrict__ b,
    float* __restrict__ colsum, const float* __restrict__ Wf,
    const float* __restrict__ bf, const float* __restrict__ gx,
    const float* __restrict__ bx, float* __restrict__ out, int* __restrict__ bar) {
    __shared__ float p[256];
    __shared__ float red[4][64];
    float mu = st[0] / (float)n;
    float var = st[1] / (float)n - mu * mu;
    var = var < 0.f ? 0.f : var;
    float inv = 1.0f / (sqrtf(var) + EPSV);
    int t = threadIdx.x;
    float gv = g[t], bv = b[t];
    float local = 0.f;
    int stride = gridDim.x * blockDim.x;   // multiple of 256 -> channel == t always
    for (int i = blockIdx.x * blockDim.x + t; i < n; i += stride) {
        float y = (bf2f(h[i]) - mu) * inv * gv + bv;
        local += fmaxf(y, 0.f);
    }
    atomicAdd(&colsum[t], local);
    __threadfence();
    __syncthreads();
    if (t == 0)
        __hip_atomic_fetch_add(&bar[0], 1, __ATOMIC_RELEASE, __HIP_MEMORY_SCOPE_AGENT);
    if (blockIdx.x != 0) return;
    if (t == 0)
        while (__hip_atomic_load(&bar[0], __ATOMIC_ACQUIRE, __HIP_MEMORY_SCOPE_AGENT) < (int)gridDim.x) {}
    __syncthreads();
    // ---- head: split-K matvec (4 k-groups x 64 cols) + wave LN ----
    p[t] = colsum[t] * (1.0f / (float)NODES);
    __syncthreads();
    int kg = t >> 6, o = t & 63;
    float a = 0.f;
#pragma unroll
    for (int j = 0; j < 64; j++) {
        int c = kg + j * 4;
        a = fmaf(p[c], Wf[c * 64 + o], a);
    }
    red[kg][o] = a;
    __syncthreads();
    if (t < 64) {
        float acc = bf[t] + red[0][t] + red[1][t] + red[2][t] + red[3][t];
        float sum = acc;
        for (int w = 32; w > 0; w >>= 1) sum += __shfl_xor(sum, w);
        float muh = sum * (1.0f / 64.0f);
        float d = acc - muh;
        float vs = d * d;
        for (int w = 32; w > 0; w >>= 1) vs += __shfl_xor(vs, w);
        float varh = vs * (1.0f / 64.0f);
        float y = d * rsqrtf(varh + EPSV) * gx[t] + bx[t];
        out[t] = fmaxf(y, 0.f);
    }
}

extern "C" void kernel_launch(void* const* d_in, const int* in_sizes, int n_in,
                              void* d_out, int out_size, void* d_ws, size_t ws_size,
                              hipStream_t stream) {
    const float* x   = (const float*)d_in[0];
    const int*   ei  = (const int*)d_in[1];
    const float* t1  = (const float*)d_in[2];
    const float* Wl1 = (const float*)d_in[3];
    const float* bl1 = (const float*)d_in[4];
    const float* Wr1 = (const float*)d_in[5];
    const float* g1  = (const float*)d_in[6];
    const float* be1 = (const float*)d_in[7];
    const float* t2  = (const float*)d_in[8];
    const float* Wl2 = (const float*)d_in[9];
    const float* bl2 = (const float*)d_in[10];
    const float* Wr2 = (const float*)d_in[11];
    const float* g2  = (const float*)d_in[12];
    const float* be2 = (const float*)d_in[13];
    const float* Wf  = (const float*)d_in[14];
    const float* bf  = (const float*)d_in[15];
    const float* gx  = (const float*)d_in[16];
    const float* bx  = (const float*)d_in[17];
    float* out = (float*)d_out;

    char* ws = (char*)d_ws;
    size_t off = 0;
    auto alloc = [&](size_t bytes) { size_t o = off; off = (off + bytes + 511) & ~511ull; return o; };
    size_t o_counts = alloc((size_t)NODES * 4);
    size_t o_cursor = alloc((size_t)NODES * 4);
    size_t o_bar    = alloc(16 * 4);                 // grid-barrier counter
    size_t zero_bytes = off;                         // memset: counts+cursor+bar
    size_t o_acc    = alloc(4 * 4);
    size_t o_colsum = alloc(256 * 4);
    size_t o_bsum = alloc((size_t)SCAN_B * 4);
    size_t o_offs = alloc((size_t)(NODES + 1) * 4);
    size_t o_csrc = alloc((size_t)EDGES * 4);
    size_t o_w1l  = alloc((size_t)512 * 256 * 2);
    size_t o_w1r  = alloc((size_t)512 * 256 * 2);
    size_t o_w2l  = alloc((size_t)256 * 512 * 2);
    size_t o_w2r  = alloc((size_t)256 * 512 * 2);
    size_t o_bufX = alloc((size_t)MPAD * 256 * 2);   // xb, later h2_pre (bf16)
    size_t o_agg  = alloc((size_t)MPAD * 512 * 2);   // agg1b / agg2b
    size_t o_h1   = alloc((size_t)(MPAD + 512) * 512 * 2); // h1 (+pad-tile slack)

    int*   counts = (int*)(ws + o_counts);
    int*   cursor = (int*)(ws + o_cursor);
    int*   bar    = (int*)(ws + o_bar);
    float* acc    = (float*)(ws + o_acc);      // [0,1]=L1 stats, [2,3]=L2 stats
    float* colsum = (float*)(ws + o_colsum);
    int*   bsum   = (int*)(ws + o_bsum);
    int*   offs   = (int*)(ws + o_offs);
    int*   csrc   = (int*)(ws + o_csrc);
    unsigned short* w1lt = (unsigned short*)(ws + o_w1l);
    unsigned short* w1rt = (unsigned short*)(ws + o_w1r);
    unsigned short* w2lt = (unsigned short*)(ws + o_w2l);
    unsigned short* w2rt = (unsigned short*)(ws + o_w2r);
    unsigned short* xb   = (unsigned short*)(ws + o_bufX);
    unsigned short* h2p  = (unsigned short*)(ws + o_bufX);  // reuse after xb dead
    unsigned short* aggb = (unsigned short*)(ws + o_agg);
    unsigned short* h1   = (unsigned short*)(ws + o_h1);

    const int* src = ei;
    const int* dst = ei + EDGES;

    hipMemsetAsync(ws, 0, zero_bytes, stream);

    // D1: fused prep (count + cast + transposes + zero acc/colsum)
    k_prep<<<PREP_TOTAL, 256, 0, stream>>>(dst, counts, x, xb,
                                           Wl1, Wr1, Wl2, Wr2,
                                           w1lt, w1rt, w2lt, w2rt,
                                           acc, colsum);
    // D2-D5: parallel CSR scan, then scatter (measured-best chain)
    k_scan1<<<SCAN_B, 256, 0, stream>>>(counts, bsum);
    k_scan2<<<1, 64, 0, stream>>>(bsum, offs);
    k_scan3<<<SCAN_B, 256, 0, stream>>>(counts, bsum, offs);
    k_scatter<<<(EDGES + 255) / 256, 256, 0, stream>>>(src, dst, offs, cursor, csrc);

    // ----- layer 1 -----  (2 waves per node, 128 ch each)
    k_agg<256, 2, 8><<<(NODES * 2 + 3) / 4, 256, 0, stream>>>(xb, t1, offs, csrc, aggb);
    k_gemm_mfma<256, 512, 4, 128><<<8 * 4 * 20, 256, 0, stream>>>(
        aggb, w1lt, xb, w1rt, bl1, h1, NODES, acc);
    k_ln_relu_b<512><<<NODES * 512 / 8 / 256, 256, 0, stream>>>(h1, NODES * 512, acc, g1, be1);

    // ----- layer 2 -----  (2 waves per node, 256 ch each)
    k_agg<512, 2, 4><<<(NODES * 2 + 3) / 4, 256, 0, stream>>>(h1, t2, offs, csrc, aggb);
    k_gemm_mfma<512, 256, 2, 128><<<8 * 2 * 20, 256, 0, stream>>>(
        aggb, w2lt, h1, w2rt, bl2, h2p, NODES, acc + 2);

    // ----- fused LN2 + colsum + head -----
    k_lncol_final<<<256, 256, 0, stream>>>(h2p, NODES * 256, acc + 2, g2, be2,
                                           colsum, Wf, bf, gx, bx, out, bar);
}

// Round 14
// 317.219 us; speedup vs baseline: 1.2062x; 1.0110x over previous
//
#include <hip/hip_runtime.h>
#include <math.h>

#define NODES 20000
#define MPAD  20096          // NODES padded to multiple of 128 (GEMM M-tiles)
#define EDGES 320000
#define EPSV  1e-5f
#define LOG2E 1.4426950408889634f

// k_prep block ranges
#define PREP_CNT   1250                    // count: 1250*256 >= EDGES
#define PREP_CAST  5000                    // cast: NODES*256/4/256
#define PREP_TR    512                     // 4 matrices * 128 tiles
#define PREP_TOTAL (PREP_CNT + PREP_CAST + PREP_TR + 1)

typedef short bf16x8 __attribute__((ext_vector_type(8)));
typedef float f32x4  __attribute__((ext_vector_type(4)));
typedef float f2     __attribute__((ext_vector_type(2)));

__device__ __forceinline__ unsigned short f2bf(float f) {
    unsigned int u = __float_as_uint(f);
    u = (u + 0x7fffu + ((u >> 16) & 1u)) >> 16;
    return (unsigned short)u;
}
__device__ __forceinline__ float bf2f(unsigned short h) {
    return __uint_as_float(((unsigned int)h) << 16);
}

// ---------------- fused prep: edge-count + x cast + 4x weight transpose + zeros
__global__ void k_prep(const int* __restrict__ dst, int* __restrict__ counts,
                       const float* __restrict__ x, unsigned short* __restrict__ xb,
                       const float* __restrict__ Wl1, const float* __restrict__ Wr1,
                       const float* __restrict__ Wl2, const float* __restrict__ Wr2,
                       unsigned short* __restrict__ o1l, unsigned short* __restrict__ o1r,
                       unsigned short* __restrict__ o2l, unsigned short* __restrict__ o2r,
                       float* __restrict__ acc, float* __restrict__ colsum) {
    int b = blockIdx.x;
    int t = threadIdx.x;
    if (b < PREP_CNT) {
        int e = b * 256 + t;
        if (e < EDGES) atomicAdd(&counts[dst[e]], 1);
    } else if (b < PREP_CNT + PREP_CAST) {
        int i = ((b - PREP_CNT) * 256 + t) * 4;
        float4 v = *(const float4*)(x + i);
        xb[i + 0] = f2bf(v.x); xb[i + 1] = f2bf(v.y);
        xb[i + 2] = f2bf(v.z); xb[i + 3] = f2bf(v.w);
    } else if (b < PREP_CNT + PREP_CAST + PREP_TR) {
        __shared__ float tile[32][33];
        int zz = b - PREP_CNT - PREP_CAST;     // 0..511
        int z = zz >> 7;                        // matrix 0..3
        int idx = zz & 127;                     // tile within matrix
        const float* W = (z == 0) ? Wl1 : (z == 1) ? Wr1 : (z == 2) ? Wl2 : Wr2;
        unsigned short* Wt = (z == 0) ? o1l : (z == 1) ? o1r : (z == 2) ? o2l : o2r;
        int K = (z < 2) ? 256 : 512, N = (z < 2) ? 512 : 256;
        int nb = N / 32;
        int n0 = (idx % nb) * 32, k0 = (idx / nb) * 32;
        int tx = t & 31, ty = t >> 5;          // (32,8) layout
#pragma unroll
        for (int j = 0; j < 4; j++)
            tile[ty + j * 8][tx] = W[(size_t)(k0 + ty + j * 8) * N + n0 + tx];
        __syncthreads();
#pragma unroll
        for (int j = 0; j < 4; j++)
            Wt[(size_t)(n0 + ty + j * 8) * K + k0 + tx] = f2bf(tile[tx][ty + j * 8]);
    } else {
        if (t < 4) acc[t] = 0.f;
        colsum[t] = 0.f;
    }
}

// ---------------- parallel CSR scan (2 dispatches) + scatter ----------------
// r2's measured-best layout, minus the k_scan2 middle dispatch: each scan3
// block computes its exclusive base by summing bsum[0..b) (<=31 L2-hot
// wave-uniform loads). Scatter stays at 1250 blocks (1 edge/thread) — the
// r10 32-block fused variant starved it (59-64us, occupancy 1.2%).
// Device-barrier fusion lesson (r13): manual-co-residency barriers deadlock
// at >1 block/CU grids (640-block gemm hung the container twice). Barriers
// only at <=256-block grids (k_lncol_final).
#define SCAN_B 32

__global__ void k_scan1(const int* __restrict__ counts, int* __restrict__ bsum) {
    __shared__ int sm[256];
    int t = threadIdx.x, b = blockIdx.x;
    int i0 = (b * 256 + t) * 3;
    int s = 0;
#pragma unroll
    for (int j = 0; j < 3; j++) { int i = i0 + j; if (i < NODES) s += counts[i]; }
    sm[t] = s;
    __syncthreads();
    int v = s;
#pragma unroll
    for (int o = 1; o < 256; o <<= 1) {
        int add = (t >= o) ? sm[t - o] : 0;
        __syncthreads();
        v += add;
        sm[t] = v;
        __syncthreads();
    }
    if (t == 255) bsum[b] = v;
}

__global__ void k_scan3(const int* __restrict__ counts, const int* __restrict__ bsum,
                        int* __restrict__ offs) {
    __shared__ int sm[256];
    int t = threadIdx.x, b = blockIdx.x;
    int i0 = (b * 256 + t) * 3;
    int c[3]; int s = 0;
#pragma unroll
    for (int j = 0; j < 3; j++) {
        int i = i0 + j;
        c[j] = (i < NODES) ? counts[i] : 0;
        s += c[j];
    }
    sm[t] = s;
    __syncthreads();
    int v = s;
#pragma unroll
    for (int o = 1; o < 256; o <<= 1) {
        int add = (t >= o) ? sm[t - o] : 0;
        __syncthreads();
        v += add;
        sm[t] = v;
        __syncthreads();
    }
    int base = 0;                            // exclusive base: sum bsum[0..b)
    for (int i = 0; i < b; i++) base += bsum[i];
    if (b == SCAN_B - 1 && t == 255) offs[NODES] = base + v;
    int run = base + (v - s);                // block base + thread-exclusive
#pragma unroll
    for (int j = 0; j < 3; j++) {
        int i = i0 + j;
        if (i < NODES) { offs[i] = run; run += c[j]; }
    }
}

__global__ void k_scatter(const int* __restrict__ src, const int* __restrict__ dst,
                          const int* __restrict__ offs, int* __restrict__ cursor,
                          int* __restrict__ csr_src) {
    int e = blockIdx.x * blockDim.x + threadIdx.x;
    if (e < EDGES) {
        int d = dst[e];
        int pos = atomicAdd(&cursor[d], 1);
        csr_src[offs[d] + pos] = src[e];
    }
}

// ------- per-channel softmax aggregation, un-stabilized (inputs bounded) -----
// Measured floor ~44.5us (layer 2): 11 structural variants land 44-50us —
// issue/latency-bound, not fetch-bound; keep this config.
template <int C, int S, int UNR>
__global__ void k_agg(const unsigned short* __restrict__ xb, const float* __restrict__ tt,
                      const int* __restrict__ offs, const int* __restrict__ csr,
                      unsigned short* __restrict__ out) {
    constexpr int CS  = C / S;
    constexpr int VPL = CS / 64;
    constexpr int W   = VPL / 2;
    typedef unsigned int uv __attribute__((ext_vector_type(W)));
    typedef unsigned short usv __attribute__((ext_vector_type(VPL)));
    int waveg = (int)((blockIdx.x * (unsigned)blockDim.x + threadIdx.x) >> 6);
    int lane = threadIdx.x & 63;
    int node = waveg / S;
    int slice = waveg % S;
    if (node >= NODES) return;
    int beg = __builtin_amdgcn_readfirstlane(offs[node]);
    int end = __builtin_amdgcn_readfirstlane(offs[node + 1]);
    int cb = slice * CS + lane * VPL;
    const unsigned short* __restrict__ xcb = xb + cb;
    f2 tl[W], l[W], s[W];
#pragma unroll
    for (int i = 0; i < W; i++) {
        tl[i][0] = tt[cb + 2 * i] * LOG2E;
        tl[i][1] = tt[cb + 2 * i + 1] * LOG2E;
        l[i][0] = 0.f; l[i][1] = 0.f;
        s[i][0] = 0.f; s[i][1] = 0.f;
    }
    int k = beg;
    for (; k + UNR <= end; k += UNR) {
        uv v[UNR];
#pragma unroll
        for (int u = 0; u < UNR; u++) {
            int sn = csr[k + u];                     // uniform -> s_load
            v[u] = *(const uv*)(xcb + (size_t)sn * C);
        }
#pragma unroll
        for (int u = 0; u < UNR; u++)
#pragma unroll
            for (int i = 0; i < W; i++) {
                unsigned wd = v[u][i];
                f2 xv;
                xv[0] = __uint_as_float(wd << 16);
                xv[1] = __uint_as_float(wd & 0xffff0000u);
                f2 a = xv * tl[i];
                f2 p;
                p[0] = __builtin_amdgcn_exp2f(a[0]);
                p[1] = __builtin_amdgcn_exp2f(a[1]);
                l[i] += p;
                s[i] = __builtin_elementwise_fma(p, xv, s[i]);
            }
    }
    for (; k < end; k++) {
        int sn = csr[k];
        uv vv = *(const uv*)(xcb + (size_t)sn * C);
#pragma unroll
        for (int i = 0; i < W; i++) {
            unsigned wd = vv[i];
            f2 xv;
            xv[0] = __uint_as_float(wd << 16);
            xv[1] = __uint_as_float(wd & 0xffff0000u);
            f2 a = xv * tl[i];
            f2 p;
            p[0] = __builtin_amdgcn_exp2f(a[0]);
            p[1] = __builtin_amdgcn_exp2f(a[1]);
            l[i] += p;
            s[i] = __builtin_elementwise_fma(p, xv, s[i]);
        }
    }
    bool has = end > beg;
    usv o;
#pragma unroll
    for (int i = 0; i < W; i++) {
        o[2 * i]     = f2bf(has ? s[i][0] / l[i][0] : 0.f);
        o[2 * i + 1] = f2bf(has ? s[i][1] / l[i][1] : 0.f);
    }
    *(usv*)(out + (size_t)node * C + cb) = o;
}

// ---------------- dual bf16 MFMA GEMM: C = A1*B1t^T + A2*B2t^T + bias ---------
// r7 reg-staged pipeline (best measured wall config). GEMM ledger (7
// variants): 2-barrier 44.5 / dbuf +7.5 / pair-64 ~45 / slab-128 44.5 /
// reg-staged 45-47 (best wall) / TM=64 51 / direct-reg 72. The ~45us floor
// is robust vs staging mechanism, drain count, TLP, and no-LDS.
// Epilogue: rs[4] (4 waves) — fixed from the r7 rs[8] latent bug.
template <int K, int NT, int NTILES, int TN>
__global__ __launch_bounds__(256) void k_gemm_mfma(
    const unsigned short* __restrict__ A1, const unsigned short* __restrict__ B1t,
    const unsigned short* __restrict__ A2, const unsigned short* __restrict__ B2t,
    const float* __restrict__ bias, unsigned short* __restrict__ Co, int M,
    float* __restrict__ stat) {
    constexpr int NF  = TN / 32;           // n-frags per wave (2 waves span TN)
    constexpr int BIT = TN / 64;           // B row-groups per chunk
    constexpr int HS  = K / 64;            // slabs per phase
    constexpr int NS  = 2 * HS;            // total slabs (both phases)
    __shared__ short As[2 * 128 * 32];     // 2 k-chunks, [128][32] each
    __shared__ short Bs[2 * TN * 32];
    __shared__ float rs[4], rq[4];

    // swizzled decode: bx = x + 8*(n + NTILES*mh); m = mh*8 + x
    int bx = blockIdx.x;
    int xid = bx & 7, q = bx >> 3;
    int n = q % NTILES, mh = q / NTILES;
    int m = mh * 8 + xid;
    if (m * 128 >= MPAD) return;           // pad tiles: whole block exits
    int m0 = m * 128, n0 = n * TN;

    int t = threadIdx.x;
    int wv = t >> 6, lane = t & 63;
    int wm = wv & 1, wn = wv >> 1;
    int lm = lane & 15, quad = lane >> 4;
    int sr = t >> 2;
    int sc8 = (t & 3) * 8;

    f32x4 acc[4][NF] = {};
    bf16x8 rA[2][2];                       // [chunk][rowgroup] prefetch regs
    bf16x8 rB[2][BIT];

    auto loadslab = [&](int s) {
        const unsigned short* __restrict__ A  = (s < HS) ? A1 : A2;
        const unsigned short* __restrict__ Bt = (s < HS) ? B1t : B2t;
        int kk = (s & (HS - 1)) * 64;
#pragma unroll
        for (int c = 0; c < 2; c++) {
#pragma unroll
            for (int it = 0; it < 2; it++)
                rA[c][it] = *(const bf16x8*)(A + (size_t)(m0 + it * 64 + sr) * K + kk + c * 32 + sc8);
#pragma unroll
            for (int it = 0; it < BIT; it++)
                rB[c][it] = *(const bf16x8*)(Bt + (size_t)(n0 + it * 64 + sr) * K + kk + c * 32 + sc8);
        }
    };

    loadslab(0);
    for (int s = 0; s < NS; s++) {
        if (s) __syncthreads();            // all waves done reading LDS of s-1
#pragma unroll
        for (int c = 0; c < 2; c++) {      // regs -> LDS (vmcnt wait auto)
#pragma unroll
            for (int it = 0; it < 2; it++)
                *(bf16x8*)&As[c * 4096 + it * 2048 + t * 8] = rA[c][it];
#pragma unroll
            for (int it = 0; it < BIT; it++)
                *(bf16x8*)&Bs[c * (TN * 32) + it * 2048 + t * 8] = rB[c][it];
        }
        __syncthreads();                   // slab visible to all waves
        if (s + 1 < NS) loadslab(s + 1);   // prefetch flies under compute
#pragma unroll
        for (int c = 0; c < 2; c++) {
            bf16x8 af[4], bfr[NF];
#pragma unroll
            for (int i = 0; i < 4; i++)
                af[i] = *(const bf16x8*)&As[c * 4096 + (wm * 64 + i * 16 + lm) * 32 + quad * 8];
#pragma unroll
            for (int j = 0; j < NF; j++)
                bfr[j] = *(const bf16x8*)&Bs[c * (TN * 32) + (wn * (TN / 2) + j * 16 + lm) * 32 + quad * 8];
#pragma unroll
            for (int mi = 0; mi < 4; mi++)
#pragma unroll
                for (int nj = 0; nj < NF; nj++)
                    acc[mi][nj] = __builtin_amdgcn_mfma_f32_16x16x32_bf16(
                        af[mi], bfr[nj], acc[mi][nj], 0, 0, 0);
        }
    }

    float sum = 0.f, ss = 0.f;
#pragma unroll
    for (int mi = 0; mi < 4; mi++) {
        int rb = m0 + wm * 64 + mi * 16 + quad * 4;
#pragma unroll
        for (int nj = 0; nj < NF; nj++) {
            int col = n0 + wn * (TN / 2) + nj * 16 + lm;
            float bb = bias[col];
#pragma unroll
            for (int rg = 0; rg < 4; rg++) {
                int row = rb + rg;
                if (row < M) {
                    float y = acc[mi][nj][rg] + bb;
                    Co[(size_t)row * NT + col] = f2bf(y);
                    sum += y; ss += y * y;
                }
            }
        }
    }
    // wave shfl-reduce, then 1 barrier + single atomic pair per block
#pragma unroll
    for (int o = 32; o > 0; o >>= 1) {
        sum += __shfl_xor(sum, o);
        ss  += __shfl_xor(ss, o);
    }
    if (lane == 0) { rs[wv] = sum; rq[wv] = ss; }
    __syncthreads();
    if (t == 0) {
        float a0 = 0.f, a1 = 0.f;
#pragma unroll
        for (int i = 0; i < 4; i++) { a0 += rs[i]; a1 += rq[i]; }
        atomicAdd(&stat[0], a0); atomicAdd(&stat[1], a1);
    }
}

// ---------------- graph-LN + ReLU, in-place bf16, vectorized x8 --------------
template <int C>
__global__ void k_ln_relu_b(unsigned short* __restrict__ h, int n,
                            const float* __restrict__ st,
                            const float* __restrict__ g, const float* __restrict__ b) {
    typedef unsigned short us8 __attribute__((ext_vector_type(8)));
    float mu = st[0] / (float)n;
    float var = st[1] / (float)n - mu * mu;
    var = var < 0.f ? 0.f : var;
    float inv = 1.0f / (sqrtf(var) + EPSV);
    int i8 = (blockIdx.x * blockDim.x + threadIdx.x) * 8;
    if (i8 >= n) return;
    int c = i8 & (C - 1);
    us8 v = *(const us8*)(h + i8);
    us8 o;
#pragma unroll
    for (int j = 0; j < 8; j++) {
        float y = (bf2f(v[j]) - mu) * inv * g[c + j] + b[c + j];
        o[j] = f2bf(fmaxf(y, 0.f));
    }
    *(us8*)(h + i8) = o;
}

// ------- fused: graph-LN2 + ReLU + column-sum, then head (one dispatch) ------
// 256 blocks (exactly 1/CU — the ONLY grid size where the manual device
// barrier is safe, per r13's deadlock lesson). Validated passing in r10/r11.
__global__ __launch_bounds__(256) void k_lncol_final(
    const unsigned short* __restrict__ h, int n, const float* __restrict__ st,
    const float* __restrict__ g, const float* __restrict__ b,
    float* __restrict__ colsum, const float* __restrict__ Wf,
    const float* __restrict__ bfv, const float* __restrict__ gx,
    const float* __restrict__ bxv, float* __restrict__ out, int* __restrict__ bar) {
    __shared__ float p[256];
    __shared__ float red[4][64];
    float mu = st[0] / (float)n;
    float var = st[1] / (float)n - mu * mu;
    var = var < 0.f ? 0.f : var;
    float inv = 1.0f / (sqrtf(var) + EPSV);
    int t = threadIdx.x;
    float gv = g[t], bv = b[t];
    float local = 0.f;
    int stride = gridDim.x * blockDim.x;   // multiple of 256 -> channel == t always
    for (int i = blockIdx.x * blockDim.x + t; i < n; i += stride) {
        float y = (bf2f(h[i]) - mu) * inv * gv + bv;
        local += fmaxf(y, 0.f);
    }
    atomicAdd(&colsum[t], local);
    __threadfence();
    __syncthreads();
    if (t == 0)
        __hip_atomic_fetch_add(&bar[0], 1, __ATOMIC_RELEASE, __HIP_MEMORY_SCOPE_AGENT);
    if (blockIdx.x != 0) return;
    if (t == 0)
        while (__hip_atomic_load(&bar[0], __ATOMIC_ACQUIRE, __HIP_MEMORY_SCOPE_AGENT) < (int)gridDim.x) {}
    __syncthreads();
    // ---- head: split-K matvec (4 k-groups x 64 cols) + wave LN ----
    p[t] = colsum[t] * (1.0f / (float)NODES);
    __syncthreads();
    int kg = t >> 6, o = t & 63;
    float a = 0.f;
#pragma unroll
    for (int j = 0; j < 64; j++) {
        int c = kg + j * 4;
        a = fmaf(p[c], Wf[c * 64 + o], a);
    }
    red[kg][o] = a;
    __syncthreads();
    if (t < 64) {
        float acc = bfv[t] + red[0][t] + red[1][t] + red[2][t] + red[3][t];
        float sum = acc;
        for (int w = 32; w > 0; w >>= 1) sum += __shfl_xor(sum, w);
        float muh = sum * (1.0f / 64.0f);
        float d = acc - muh;
        float vs = d * d;
        for (int w = 32; w > 0; w >>= 1) vs += __shfl_xor(vs, w);
        float varh = vs * (1.0f / 64.0f);
        float y = d * rsqrtf(varh + EPSV) * gx[t] + bxv[t];
        out[t] = fmaxf(y, 0.f);
    }
}

extern "C" void kernel_launch(void* const* d_in, const int* in_sizes, int n_in,
                              void* d_out, int out_size, void* d_ws, size_t ws_size,
                              hipStream_t stream) {
    const float* x   = (const float*)d_in[0];
    const int*   ei  = (const int*)d_in[1];
    const float* t1  = (const float*)d_in[2];
    const float* Wl1 = (const float*)d_in[3];
    const float* bl1 = (const float*)d_in[4];
    const float* Wr1 = (const float*)d_in[5];
    const float* g1  = (const float*)d_in[6];
    const float* be1 = (const float*)d_in[7];
    const float* t2  = (const float*)d_in[8];
    const float* Wl2 = (const float*)d_in[9];
    const float* bl2 = (const float*)d_in[10];
    const float* Wr2 = (const float*)d_in[11];
    const float* g2  = (const float*)d_in[12];
    const float* be2 = (const float*)d_in[13];
    const float* Wf  = (const float*)d_in[14];
    const float* bf  = (const float*)d_in[15];
    const float* gx  = (const float*)d_in[16];
    const float* bx  = (const float*)d_in[17];
    float* out = (float*)d_out;

    char* ws = (char*)d_ws;
    size_t off = 0;
    auto alloc = [&](size_t bytes) { size_t o = off; off = (off + bytes + 511) & ~511ull; return o; };
    size_t o_counts = alloc((size_t)NODES * 4);
    size_t o_cursor = alloc((size_t)NODES * 4);
    size_t o_bar    = alloc(16 * 4);                 // grid-barrier counter
    size_t zero_bytes = off;                         // memset: counts+cursor+bar
    size_t o_acc    = alloc(4 * 4);
    size_t o_colsum = alloc(256 * 4);
    size_t o_bsum = alloc((size_t)SCAN_B * 4);
    size_t o_offs = alloc((size_t)(NODES + 1) * 4);
    size_t o_csrc = alloc((size_t)EDGES * 4);
    size_t o_w1l  = alloc((size_t)512 * 256 * 2);
    size_t o_w1r  = alloc((size_t)512 * 256 * 2);
    size_t o_w2l  = alloc((size_t)256 * 512 * 2);
    size_t o_w2r  = alloc((size_t)256 * 512 * 2);
    size_t o_bufX = alloc((size_t)MPAD * 256 * 2);   // xb, later h2_pre (bf16)
    size_t o_agg  = alloc((size_t)MPAD * 512 * 2);   // agg1b / agg2b
    size_t o_h1   = alloc((size_t)(MPAD + 512) * 512 * 2); // h1 (+pad-tile slack)

    int*   counts = (int*)(ws + o_counts);
    int*   cursor = (int*)(ws + o_cursor);
    int*   bar    = (int*)(ws + o_bar);
    float* acc    = (float*)(ws + o_acc);      // [0,1]=L1 stats, [2,3]=L2 stats
    float* colsum = (float*)(ws + o_colsum);
    int*   bsum   = (int*)(ws + o_bsum);
    int*   offs   = (int*)(ws + o_offs);
    int*   csrc   = (int*)(ws + o_csrc);
    unsigned short* w1lt = (unsigned short*)(ws + o_w1l);
    unsigned short* w1rt = (unsigned short*)(ws + o_w1r);
    unsigned short* w2lt = (unsigned short*)(ws + o_w2l);
    unsigned short* w2rt = (unsigned short*)(ws + o_w2r);
    unsigned short* xb   = (unsigned short*)(ws + o_bufX);
    unsigned short* h2p  = (unsigned short*)(ws + o_bufX);  // reuse after xb dead
    unsigned short* aggb = (unsigned short*)(ws + o_agg);
    unsigned short* h1   = (unsigned short*)(ws + o_h1);

    const int* src = ei;
    const int* dst = ei + EDGES;

    hipMemsetAsync(ws, 0, zero_bytes, stream);

    // D1: fused prep (count + cast + transposes + zero acc/colsum)
    k_prep<<<PREP_TOTAL, 256, 0, stream>>>(dst, counts, x, xb,
                                           Wl1, Wr1, Wl2, Wr2,
                                           w1lt, w1rt, w2lt, w2rt,
                                           acc, colsum);
    // D2-D4: CSR scan (2 dispatches) + scatter
    k_scan1<<<SCAN_B, 256, 0, stream>>>(counts, bsum);
    k_scan3<<<SCAN_B, 256, 0, stream>>>(counts, bsum, offs);
    k_scatter<<<(EDGES + 255) / 256, 256, 0, stream>>>(src, dst, offs, cursor, csrc);

    // ----- layer 1 -----  (2 waves per node, 128 ch each)
    k_agg<256, 2, 8><<<(NODES * 2 + 3) / 4, 256, 0, stream>>>(xb, t1, offs, csrc, aggb);
    k_gemm_mfma<256, 512, 4, 128><<<8 * 4 * 20, 256, 0, stream>>>(
        aggb, w1lt, xb, w1rt, bl1, h1, NODES, acc);
    k_ln_relu_b<512><<<NODES * 512 / 8 / 256, 256, 0, stream>>>(h1, NODES * 512, acc, g1, be1);

    // ----- layer 2 -----  (2 waves per node, 256 ch each)
    k_agg<512, 2, 4><<<(NODES * 2 + 3) / 4, 256, 0, stream>>>(h1, t2, offs, csrc, aggb);
    k_gemm_mfma<512, 256, 2, 128><<<8 * 2 * 20, 256, 0, stream>>>(
        aggb, w2lt, h1, w2rt, bl2, h2p, NODES, acc + 2);

    // ----- fused LN2 + colsum + head -----
    k_lncol_final<<<256, 256, 0, stream>>>(h2p, NODES * 256, acc + 2, g2, be2,
                                           colsum, Wf, bf, gx, bx, out, bar);
}